// Round 1
// baseline (2045.847 us; speedup 1.0000x reference)
//
#include <hip/hip_runtime.h>
#include <hip/hip_bf16.h>

#define N_NODES 50000
#define N_EDGES 1600000
#define NFEAT   512
#define HIDDEN  128
#define NCLASS  40

// 128 rows per bucket -> 391 buckets; bucket id = row >> 7
#define NBUCK 391
#define ROWS_PER_BUCKET 128

#define HISTB 782                 // ceil(1600000 / 2048) edges-hist blocks
#define W1T_BLOCKS 256
#define GEMM1_BLOCKS 391          // ceil(50000/128)
#define PART_T 4096
#define PART_BLOCKS 391           // ceil(1600000/4096)

typedef short short8 __attribute__((ext_vector_type(8)));
typedef float f32x4  __attribute__((ext_vector_type(4)));

// bf16 bits (RNE) from float
__device__ __forceinline__ unsigned short f2bu(float f) {
  __hip_bfloat16 h = __float2bfloat16(f);
  return *reinterpret_cast<unsigned short*>(&h);
}

// ---------------------------------------------------------------------------
// JAX threefry2x32, key (0,42), partitionable: bits[i] = o0^o1 of ctr (0,i).
// keep iff (bits>>31)==0.  (verified in earlier rounds)
// ---------------------------------------------------------------------------
__device__ __forceinline__ unsigned rotl32(unsigned x, int n) {
  return (x << n) | (x >> (32 - n));
}

__device__ __forceinline__ unsigned threefry_bits(unsigned x1) {
  unsigned x0 = 0u;
  const unsigned ks0 = 0u, ks1 = 42u, ks2 = 0x1BD11BDAu ^ 42u;
  x0 += ks0; x1 += ks1;
#define TFR(r) { x0 += x1; x1 = rotl32(x1, (r)); x1 ^= x0; }
  TFR(13) TFR(15) TFR(26) TFR(6)
  x0 += ks1; x1 += ks2 + 1u;
  TFR(17) TFR(29) TFR(16) TFR(24)
  x0 += ks2; x1 += ks0 + 2u;
  TFR(13) TFR(15) TFR(26) TFR(6)
  x0 += ks0; x1 += ks1 + 3u;
  TFR(17) TFR(29) TFR(16) TFR(24)
  x0 += ks1; x1 += ks2 + 4u;
  TFR(13) TFR(15) TFR(26) TFR(6)
  x0 += ks2; x1 += ks0 + 5u;
#undef TFR
  return x0 ^ x1;
}

// ---------------------------------------------------------------------------
// K1 fused: 391-bin bucket histogram (blocks 0..781) | W1 transpose
// (blocks 782..1037). LDS-reduced histogram: ~391 global atomics per block.
// ---------------------------------------------------------------------------
__global__ __launch_bounds__(256) void hist_w1t_kernel(
    const int* __restrict__ erow, int* __restrict__ bcnt,
    const float* __restrict__ W1, unsigned short* __restrict__ W1T) {
  if (blockIdx.x < HISTB) {
    __shared__ int lcnt[NBUCK];
    const int t = threadIdx.x;
    if (t < NBUCK) lcnt[t] = 0;
    if (t + 256 < NBUCK) lcnt[t + 256] = 0;
    __syncthreads();
    const int base = blockIdx.x * 2048;
#pragma unroll
    for (int k = 0; k < 8; k++) {
      int idx = base + k * 256 + t;
      if (idx < N_EDGES) atomicAdd(&lcnt[erow[idx] >> 7], 1);
    }
    __syncthreads();
    if (t < NBUCK && lcnt[t]) atomicAdd(&bcnt[t], lcnt[t]);
    if (t + 256 < NBUCK && lcnt[t + 256])
      atomicAdd(&bcnt[t + 256], lcnt[t + 256]);
  } else {
    int id = (blockIdx.x - HISTB) * 256 + threadIdx.x;  // 65536 exact
    int n = id & 127, k = id >> 7;
    W1T[n * NFEAT + k] = f2bu(W1[k * HIDDEN + n]);
  }
}

// ---------------------------------------------------------------------------
// GEMM1 body (device fn): support = bf16(x) @ bf16(W1), fp32 acc, MFMA.
// (verified in earlier rounds, unchanged)
// ---------------------------------------------------------------------------
__device__ __forceinline__ void gemm1_body(
    int bid, const float* __restrict__ x,
    const unsigned short* __restrict__ W1T,
    unsigned short* __restrict__ support) {
  __shared__ short8 As[512];  // chunk = q*128 + row
  __shared__ short8 Bs[512];  // chunk = q*128 + col
  const int t = threadIdx.x;
  const int lane = t & 63;
  const int w = t >> 6;
  const int quad = lane >> 4;
  const int l15 = lane & 15;
  const int node_base = bid * 128;
  const int mbase = (w >> 1) * 64;
  const int nbase = (w & 1) * 64;

  f32x4 acc[4][4] = {};

  for (int k0 = 0; k0 < NFEAT; k0 += 32) {
#pragma unroll
    for (int i = 0; i < 2; i++) {
      int lin = i * 256 + t;        // 0..511
      int n = lin >> 2, q = lin & 3;
      int row = node_base + n;
      if (row >= N_NODES) row = N_NODES - 1;
      const float* src = &x[(size_t)row * NFEAT + k0 + q * 8];
      float4 a = *(const float4*)src;
      float4 b = *(const float4*)(src + 4);
      short8 p;
      p[0] = (short)f2bu(a.x); p[1] = (short)f2bu(a.y);
      p[2] = (short)f2bu(a.z); p[3] = (short)f2bu(a.w);
      p[4] = (short)f2bu(b.x); p[5] = (short)f2bu(b.y);
      p[6] = (short)f2bu(b.z); p[7] = (short)f2bu(b.w);
      As[q * 128 + n] = p;
      Bs[q * 128 + n] = *(const short8*)&W1T[(size_t)n * NFEAT + k0 + q * 8];
    }
    __syncthreads();
    short8 af[4], bfr[4];
#pragma unroll
    for (int mt = 0; mt < 4; mt++)
      af[mt] = As[quad * 128 + mbase + mt * 16 + l15];
#pragma unroll
    for (int nt = 0; nt < 4; nt++)
      bfr[nt] = Bs[quad * 128 + nbase + nt * 16 + l15];
#pragma unroll
    for (int mt = 0; mt < 4; mt++)
#pragma unroll
      for (int nt = 0; nt < 4; nt++)
        acc[mt][nt] = __builtin_amdgcn_mfma_f32_16x16x32_bf16(
            af[mt], bfr[nt], acc[mt][nt], 0, 0, 0);
    __syncthreads();
  }

#pragma unroll
  for (int mt = 0; mt < 4; mt++)
#pragma unroll
    for (int nt = 0; nt < 4; nt++)
#pragma unroll
      for (int r = 0; r < 4; r++) {
        int row = node_base + mbase + mt * 16 + quad * 4 + r;
        int col = nbase + nt * 16 + l15;
        if (row < N_NODES)
          support[(size_t)row * HIDDEN + col] = f2bu(acc[mt][nt][r]);
      }
}

// ---------------------------------------------------------------------------
// K2 fused: block 0 scans the 391 bucket counts -> bbase (exclusive) and
// initializes gcur; blocks 1..391 run GEMM1 (independent work, overlaps).
// ---------------------------------------------------------------------------
__global__ __launch_bounds__(256) void scan_gemm1_kernel(
    const int* __restrict__ bcnt, int* __restrict__ bbase,
    int* __restrict__ gcur, const float* __restrict__ x,
    const unsigned short* __restrict__ W1T,
    unsigned short* __restrict__ support) {
  if (blockIdx.x == 0) {
    __shared__ int ssc[512];
    const int t = threadIdx.x;
    int c0 = (t < NBUCK) ? bcnt[t] : 0;
    int c1 = (t + 256 < NBUCK) ? bcnt[t + 256] : 0;
    ssc[t] = c0; ssc[t + 256] = c1;
    __syncthreads();
#pragma unroll
    for (int off = 1; off < 512; off <<= 1) {
      int v0 = (t >= off) ? ssc[t - off] : 0;
      int v1 = ssc[t + 256 - off];
      __syncthreads();
      ssc[t] += v0; ssc[t + 256] += v1;
      __syncthreads();
    }
    if (t < NBUCK) { int e = ssc[t] - c0; bbase[t] = e; gcur[t] = e; }
    if (t + 256 < NBUCK) {
      int e = ssc[t + 256] - c1; bbase[t + 256] = e; gcur[t + 256] = e;
    }
    if (t == 0) bbase[NBUCK] = N_EDGES;
  } else {
    gemm1_body(blockIdx.x - 1, x, W1T, support);
  }
}

// ---------------------------------------------------------------------------
// K3: partition edges into bucket-contiguous regions of eb[] with
// block-level LDS counting sort -> coalesced global writes (runs ~10 edges).
// Record: uint2 { col | bf16(val)<<16 , row }.
// ---------------------------------------------------------------------------
__global__ __launch_bounds__(256) void partition_kernel(
    const int* __restrict__ erow, const int* __restrict__ ecol,
    const float* __restrict__ evals, int* __restrict__ gcur,
    uint2* __restrict__ eb) {
  __shared__ uint2 sorted[PART_T];   // 32 KB
  __shared__ int cnt[NBUCK];
  __shared__ int shift[NBUCK];
  __shared__ int ssc[512];
  const int t = threadIdx.x;
  const int base = blockIdx.x * PART_T;

  if (t < NBUCK) cnt[t] = 0;
  if (t + 256 < NBUCK) cnt[t + 256] = 0;
  __syncthreads();

  uint2 er[16];
  unsigned short loc[16];
#pragma unroll
  for (int k = 0; k < 16; k++) {
    int idx = base + k * 256 + t;
    if (idx < N_EDGES) {
      int r = erow[idx];
      er[k].y = (unsigned)r;
      er[k].x = (unsigned)ecol[idx] | ((unsigned)f2bu(evals[idx]) << 16);
      loc[k] = (unsigned short)atomicAdd(&cnt[r >> 7], 1);
    } else {
      er[k].y = 0xffffffffu;
    }
  }
  __syncthreads();

  // inclusive scan of cnt (padded to 512)
  ssc[t] = (t < NBUCK) ? cnt[t] : 0;
  ssc[t + 256] = (t + 256 < NBUCK) ? cnt[t + 256] : 0;
  __syncthreads();
#pragma unroll
  for (int off = 1; off < 512; off <<= 1) {
    int v0 = (t >= off) ? ssc[t - off] : 0;
    int v1 = ssc[t + 256 - off];
    __syncthreads();
    ssc[t] += v0; ssc[t + 256] += v1;
    __syncthreads();
  }

  // claim global region chunk per touched bucket
  for (int b = t; b < NBUCK; b += 256) {
    int c = cnt[b];
    if (c > 0) {
      int lb = ssc[b] - c;                  // local base
      int gb = atomicAdd(&gcur[b], c);      // global base of this chunk
      shift[b] = gb - lb;
    }
  }
  // scatter into LDS by bucket (ssc/cnt stable since last barrier)
#pragma unroll
  for (int k = 0; k < 16; k++) {
    if (er[k].y != 0xffffffffu) {
      int b = (int)(er[k].y >> 7);
      sorted[ssc[b] - cnt[b] + (int)loc[k]] = er[k];
    }
  }
  __syncthreads();

  // coalesced copy out: consecutive i share bucket in runs of ~10
  const int total = ssc[NBUCK - 1];
  for (int i = t; i < total; i += 256) {
    uint2 e = sorted[i];
    eb[shift[e.y >> 7] + i] = e;
  }
}

// ---------------------------------------------------------------------------
// K4: SpMM1 direct on bucketed edges. Block b owns rows [b*128, b*128+128):
// 64 KB fp32 LDS accumulator, ds_add_f32 accumulation, wave-uniform scalar
// edge loads (8 in flight), coalesced 256 B support-row gathers.
// Epilogue: +b1, relu, threefry dropout, pack bf16x2 -> h.
// ---------------------------------------------------------------------------
__global__ __launch_bounds__(256) void spmm1_direct(
    const uint2* __restrict__ eb, const int* __restrict__ bbase,
    const unsigned* __restrict__ sup,  // support rows = 64 uints (bf16x2)
    const float* __restrict__ b1, unsigned* __restrict__ h) {
  __shared__ float acc[ROWS_PER_BUCKET * HIDDEN];  // 64 KB
  const int t = threadIdx.x;
  const int b = blockIdx.x;

  f32x4* a4 = (f32x4*)acc;
#pragma unroll
  for (int i = 0; i < 16; i++) a4[i * 256 + t] = (f32x4){0.f, 0.f, 0.f, 0.f};
  __syncthreads();

  const int beg = bbase[b], end = bbase[b + 1];
  const int w = t >> 6;
  const int lane = t & 63;
  const int len = end - beg;
  const int q = (len + 3) >> 2;
  const int wbeg = beg + w * q;
  const int wend = min(wbeg + q, end);

  int j = wbeg;
  for (; j + 7 < wend; j += 8) {
    uint2 e[8];
#pragma unroll
    for (int k = 0; k < 8; k++) e[k] = eb[j + k];
    unsigned u[8];
#pragma unroll
    for (int k = 0; k < 8; k++)
      u[k] = sup[(e[k].x & 0xffffu) * 64 + lane];
#pragma unroll
    for (int k = 0; k < 8; k++) {
      float val = __uint_as_float(e[k].x & 0xffff0000u);
      float* a = &acc[(e[k].y & 127u) * HIDDEN + 2 * lane];
      atomicAdd(a,     val * __uint_as_float(u[k] << 16));
      atomicAdd(a + 1, val * __uint_as_float(u[k] & 0xffff0000u));
    }
  }
  for (; j < wend; j++) {
    uint2 e0 = eb[j];
    unsigned u0 = sup[(e0.x & 0xffffu) * 64 + lane];
    float val = __uint_as_float(e0.x & 0xffff0000u);
    float* a = &acc[(e0.y & 127u) * HIDDEN + 2 * lane];
    atomicAdd(a,     val * __uint_as_float(u0 << 16));
    atomicAdd(a + 1, val * __uint_as_float(u0 & 0xffff0000u));
  }
  __syncthreads();

  // epilogue: 128 rows x 64 packed outputs
  for (int i = t; i < ROWS_PER_BUCKET * 64; i += 256) {
    int rl = i >> 6, c = i & 63;
    int row = b * ROWS_PER_BUCKET + rl;
    if (row < N_NODES) {
      float vx = fmaxf(acc[rl * HIDDEN + 2 * c]     + b1[2 * c],     0.f);
      float vy = fmaxf(acc[rl * HIDDEN + 2 * c + 1] + b1[2 * c + 1], 0.f);
      const unsigned i0 = (unsigned)row * HIDDEN + 2 * c;
      vx = (threefry_bits(i0) >> 31) ? 0.f : 2.f * vx;
      vy = (threefry_bits(i0 + 1) >> 31) ? 0.f : 2.f * vy;
      h[(unsigned)row * 64 + c] =
          (unsigned)f2bu(vx) | ((unsigned)f2bu(vy) << 16);
    }
  }
}

// ---------------------------------------------------------------------------
// GEMM2: h2[50000,40] = h(bf16) @ W2, fp32 compute, bf16 out. (verified)
// ---------------------------------------------------------------------------
__global__ __launch_bounds__(256) void gemm2_kernel(
    const uint4* __restrict__ h,  // rows = 16 uint4 (8 bf16 each)
    const float* __restrict__ W2, unsigned short* __restrict__ h2) {
  __shared__ float Hs[64][132];
  __shared__ float Ws[40][132];
  const int t = threadIdx.x;
  const int node_base = blockIdx.x * 64;
#pragma unroll
  for (int i = 0; i < 4; i++) {
    int lin = i * 256 + t;
    int nloc = lin >> 4, c8 = lin & 15;
    int n = node_base + nloc;
    if (n >= N_NODES) n = N_NODES - 1;
    uint4 u = h[(size_t)n * 16 + c8];
    float* d = &Hs[nloc][c8 * 8];
    d[0] = __uint_as_float(u.x << 16); d[1] = __uint_as_float(u.x & 0xffff0000u);
    d[2] = __uint_as_float(u.y << 16); d[3] = __uint_as_float(u.y & 0xffff0000u);
    d[4] = __uint_as_float(u.z << 16); d[5] = __uint_as_float(u.z & 0xffff0000u);
    d[6] = __uint_as_float(u.w << 16); d[7] = __uint_as_float(u.w & 0xffff0000u);
  }
#pragma unroll
  for (int i = 0; i < 20; i++) {
    int l = t + i * 256;
    int k = l / NCLASS, f = l % NCLASS;
    Ws[f][k] = W2[l];
  }
  __syncthreads();
  const int nloc = t >> 2;
  const int fb = t & 3;
  const int n = node_base + nloc;
  float acc[10];
#pragma unroll
  for (int j = 0; j < 10; j++) acc[j] = 0.f;
  for (int k = 0; k < HIDDEN; k += 4) {
    float4 a = *(const float4*)&Hs[nloc][k];
#pragma unroll
    for (int j = 0; j < 10; j++) {
      float4 wv = *(const float4*)&Ws[fb + 4 * j][k];
      acc[j] += a.x * wv.x + a.y * wv.y + a.z * wv.z + a.w * wv.w;
    }
  }
  if (n < N_NODES) {
#pragma unroll
    for (int j = 0; j < 10; j++)
      h2[(size_t)n * NCLASS + fb + 4 * j] = f2bu(acc[j]);
  }
}

// ---------------------------------------------------------------------------
// K6: SpMM2 direct on bucketed edges. Block b owns rows [b*128, b*128+128):
// 20 KB fp32 LDS accumulator; half-split (2 edges in flight per wave),
// 20 active lanes x 2 cols per edge. Epilogue: +b2, relu -> out (fp32).
// ---------------------------------------------------------------------------
__global__ __launch_bounds__(256) void spmm2_direct(
    const uint2* __restrict__ eb, const int* __restrict__ bbase,
    const unsigned* __restrict__ h2u,  // rows = 20 uints
    const float* __restrict__ b2, float* __restrict__ out) {
  __shared__ float acc[ROWS_PER_BUCKET * NCLASS];  // 20 KB
  const int t = threadIdx.x;
  const int b = blockIdx.x;
  for (int i = t; i < ROWS_PER_BUCKET * NCLASS; i += 256) acc[i] = 0.f;
  __syncthreads();

  const int beg = bbase[b], end = bbase[b + 1];
  const int w = t >> 6;
  const int lane = t & 63;
  const int len = end - beg;
  const int q = (len + 3) >> 2;
  const int wbeg = beg + w * q;
  const int wend = min(wbeg + q, end);
  const int half = lane >> 5;
  const int il = lane & 31;
  const unsigned ilc = (il < 20) ? (unsigned)il : 19u;
  const bool act = il < 20;

  int j = wbeg + half;
  for (; j + 3 < wend; j += 4) {
    uint2 e0 = eb[j], e1 = eb[j + 2];
    unsigned u0 = h2u[(e0.x & 0xffffu) * 20 + ilc];
    unsigned u1 = h2u[(e1.x & 0xffffu) * 20 + ilc];
    if (act) {
      float v0 = __uint_as_float(e0.x & 0xffff0000u);
      float v1 = __uint_as_float(e1.x & 0xffff0000u);
      float* a0 = &acc[(e0.y & 127u) * NCLASS + il * 2];
      atomicAdd(a0,     v0 * __uint_as_float(u0 << 16));
      atomicAdd(a0 + 1, v0 * __uint_as_float(u0 & 0xffff0000u));
      float* a1 = &acc[(e1.y & 127u) * NCLASS + il * 2];
      atomicAdd(a1,     v1 * __uint_as_float(u1 << 16));
      atomicAdd(a1 + 1, v1 * __uint_as_float(u1 & 0xffff0000u));
    }
  }
  for (; j < wend; j += 2) {
    uint2 e0 = eb[j];
    unsigned u0 = h2u[(e0.x & 0xffffu) * 20 + ilc];
    if (act) {
      float v0 = __uint_as_float(e0.x & 0xffff0000u);
      float* a0 = &acc[(e0.y & 127u) * NCLASS + il * 2];
      atomicAdd(a0,     v0 * __uint_as_float(u0 << 16));
      atomicAdd(a0 + 1, v0 * __uint_as_float(u0 & 0xffff0000u));
    }
  }
  __syncthreads();

  for (int i = t; i < ROWS_PER_BUCKET * NCLASS; i += 256) {
    int rl = i / NCLASS, c = i - rl * NCLASS;
    int row = b * ROWS_PER_BUCKET + rl;
    if (row < N_NODES)
      out[(size_t)row * NCLASS + c] = fmaxf(acc[i] + b2[c], 0.f);
  }
}

extern "C" void kernel_launch(void* const* d_in, const int* in_sizes, int n_in,
                              void* d_out, int out_size, void* d_ws,
                              size_t ws_size, hipStream_t stream) {
  const float* x     = (const float*)d_in[0];
  const int*   erow  = (const int*)d_in[1];
  const int*   ecol  = (const int*)d_in[2];
  const float* evals = (const float*)d_in[3];
  const float* W1    = (const float*)d_in[4];
  const float* b1    = (const float*)d_in[5];
  const float* W2    = (const float*)d_in[6];
  const float* b2    = (const float*)d_in[7];
  float* out = (float*)d_out;

  // ws layout (bytes): support 12.8M | h 12.8M | h2 4M | W1T 128K |
  // eb 12.8M | bcnt/bbase/gcur ~5K   (~42.5 MB)
  char* base = (char*)d_ws;
  unsigned short* support = (unsigned short*)base;
  unsigned*       h   = (unsigned*)(base + 12800000);
  unsigned short* h2  = (unsigned short*)(base + 25600000);
  unsigned short* W1T = (unsigned short*)(base + 29600000);
  uint2*          eb  = (uint2*)(base + 29731072);
  int* bcnt  = (int*)(base + 42531072);
  int* bbase = bcnt + 400;
  int* gcur  = bbase + 400;

  hipMemsetAsync(bcnt, 0, NBUCK * sizeof(int), stream);

  hist_w1t_kernel<<<HISTB + W1T_BLOCKS, 256, 0, stream>>>(erow, bcnt, W1, W1T);
  scan_gemm1_kernel<<<1 + GEMM1_BLOCKS, 256, 0, stream>>>(
      bcnt, bbase, gcur, x, W1T, support);
  partition_kernel<<<PART_BLOCKS, 256, 0, stream>>>(erow, ecol, evals, gcur,
                                                    eb);
  spmm1_direct<<<NBUCK, 256, 0, stream>>>(eb, bbase,
                                          (const unsigned*)support, b1, h);
  gemm2_kernel<<<(N_NODES + 63) / 64, 256, 0, stream>>>((const uint4*)h, W2,
                                                        h2);
  spmm2_direct<<<NBUCK, 256, 0, stream>>>(eb, bbase, (const unsigned*)h2, b2,
                                          out);
}

// Round 3
// 365.390 us; speedup vs baseline: 5.5991x; 5.5991x over previous
//
#include <hip/hip_runtime.h>
#include <hip/hip_bf16.h>

#define N_NODES 50000
#define N_EDGES 1600000
#define NFEAT   512
#define HIDDEN  128
#define NCLASS  40

// 128 rows per bucket -> 391 buckets; bucket id = row >> 7
#define NBUCK 391
#define ROWS_PER_BUCKET 128

#define HISTB 782                 // ceil(1600000 / 2048) edges-hist blocks
#define W1T_BLOCKS 256
#define GEMM1_BLOCKS 391          // ceil(50000/128)
#define PART_T 4096
#define PART_BLOCKS 391           // ceil(1600000/4096)

typedef short short8 __attribute__((ext_vector_type(8)));
typedef float f32x4  __attribute__((ext_vector_type(4)));

// bf16 bits (RNE) from float
__device__ __forceinline__ unsigned short f2bu(float f) {
  __hip_bfloat16 h = __float2bfloat16(f);
  return *reinterpret_cast<unsigned short*>(&h);
}

// ---------------------------------------------------------------------------
// JAX threefry2x32, key (0,42), partitionable: bits[i] = o0^o1 of ctr (0,i).
// keep iff (bits>>31)==0.  (verified in earlier rounds)
// ---------------------------------------------------------------------------
__device__ __forceinline__ unsigned rotl32(unsigned x, int n) {
  return (x << n) | (x >> (32 - n));
}

__device__ __forceinline__ unsigned threefry_bits(unsigned x1) {
  unsigned x0 = 0u;
  const unsigned ks0 = 0u, ks1 = 42u, ks2 = 0x1BD11BDAu ^ 42u;
  x0 += ks0; x1 += ks1;
#define TFR(r) { x0 += x1; x1 = rotl32(x1, (r)); x1 ^= x0; }
  TFR(13) TFR(15) TFR(26) TFR(6)
  x0 += ks1; x1 += ks2 + 1u;
  TFR(17) TFR(29) TFR(16) TFR(24)
  x0 += ks2; x1 += ks0 + 2u;
  TFR(13) TFR(15) TFR(26) TFR(6)
  x0 += ks0; x1 += ks1 + 3u;
  TFR(17) TFR(29) TFR(16) TFR(24)
  x0 += ks1; x1 += ks2 + 4u;
  TFR(13) TFR(15) TFR(26) TFR(6)
  x0 += ks2; x1 += ks0 + 5u;
#undef TFR
  return x0 ^ x1;
}

// ---------------------------------------------------------------------------
// K1 fused: 391-bin bucket histogram (blocks 0..781) | W1 transpose
// (blocks 782..1037). LDS-reduced histogram: ~391 global atomics per block.
// ---------------------------------------------------------------------------
__global__ __launch_bounds__(256) void hist_w1t_kernel(
    const int* __restrict__ erow, int* __restrict__ bcnt,
    const float* __restrict__ W1, unsigned short* __restrict__ W1T) {
  if (blockIdx.x < HISTB) {
    __shared__ int lcnt[NBUCK];
    const int t = threadIdx.x;
    if (t < NBUCK) lcnt[t] = 0;
    if (t + 256 < NBUCK) lcnt[t + 256] = 0;
    __syncthreads();
    const int base = blockIdx.x * 2048;
#pragma unroll
    for (int k = 0; k < 8; k++) {
      int idx = base + k * 256 + t;
      if (idx < N_EDGES) atomicAdd(&lcnt[erow[idx] >> 7], 1);
    }
    __syncthreads();
    if (t < NBUCK && lcnt[t]) atomicAdd(&bcnt[t], lcnt[t]);
    if (t + 256 < NBUCK && lcnt[t + 256])
      atomicAdd(&bcnt[t + 256], lcnt[t + 256]);
  } else {
    int id = (blockIdx.x - HISTB) * 256 + threadIdx.x;  // 65536 exact
    int n = id & 127, k = id >> 7;
    W1T[n * NFEAT + k] = f2bu(W1[k * HIDDEN + n]);
  }
}

// ---------------------------------------------------------------------------
// GEMM1 body (device fn): support = bf16(x) @ bf16(W1), fp32 acc, MFMA.
// (verified in earlier rounds, unchanged)
// ---------------------------------------------------------------------------
__device__ __forceinline__ void gemm1_body(
    int bid, const float* __restrict__ x,
    const unsigned short* __restrict__ W1T,
    unsigned short* __restrict__ support) {
  __shared__ short8 As[512];  // chunk = q*128 + row
  __shared__ short8 Bs[512];  // chunk = q*128 + col
  const int t = threadIdx.x;
  const int lane = t & 63;
  const int w = t >> 6;
  const int quad = lane >> 4;
  const int l15 = lane & 15;
  const int node_base = bid * 128;
  const int mbase = (w >> 1) * 64;
  const int nbase = (w & 1) * 64;

  f32x4 acc[4][4] = {};

  for (int k0 = 0; k0 < NFEAT; k0 += 32) {
#pragma unroll
    for (int i = 0; i < 2; i++) {
      int lin = i * 256 + t;        // 0..511
      int n = lin >> 2, q = lin & 3;
      int row = node_base + n;
      if (row >= N_NODES) row = N_NODES - 1;
      const float* src = &x[(size_t)row * NFEAT + k0 + q * 8];
      float4 a = *(const float4*)src;
      float4 b = *(const float4*)(src + 4);
      short8 p;
      p[0] = (short)f2bu(a.x); p[1] = (short)f2bu(a.y);
      p[2] = (short)f2bu(a.z); p[3] = (short)f2bu(a.w);
      p[4] = (short)f2bu(b.x); p[5] = (short)f2bu(b.y);
      p[6] = (short)f2bu(b.z); p[7] = (short)f2bu(b.w);
      As[q * 128 + n] = p;
      Bs[q * 128 + n] = *(const short8*)&W1T[(size_t)n * NFEAT + k0 + q * 8];
    }
    __syncthreads();
    short8 af[4], bfr[4];
#pragma unroll
    for (int mt = 0; mt < 4; mt++)
      af[mt] = As[quad * 128 + mbase + mt * 16 + l15];
#pragma unroll
    for (int nt = 0; nt < 4; nt++)
      bfr[nt] = Bs[quad * 128 + nbase + nt * 16 + l15];
#pragma unroll
    for (int mt = 0; mt < 4; mt++)
#pragma unroll
      for (int nt = 0; nt < 4; nt++)
        acc[mt][nt] = __builtin_amdgcn_mfma_f32_16x16x32_bf16(
            af[mt], bfr[nt], acc[mt][nt], 0, 0, 0);
    __syncthreads();
  }

#pragma unroll
  for (int mt = 0; mt < 4; mt++)
#pragma unroll
    for (int nt = 0; nt < 4; nt++)
#pragma unroll
      for (int r = 0; r < 4; r++) {
        int row = node_base + mbase + mt * 16 + quad * 4 + r;
        int col = nbase + nt * 16 + l15;
        if (row < N_NODES)
          support[(size_t)row * HIDDEN + col] = f2bu(acc[mt][nt][r]);
      }
}

// ---------------------------------------------------------------------------
// K2 fused: block 0 scans the 391 bucket counts -> bbase (exclusive) and
// initializes gcur; blocks 1..391 run GEMM1 (independent work, overlaps).
// ---------------------------------------------------------------------------
__global__ __launch_bounds__(256) void scan_gemm1_kernel(
    const int* __restrict__ bcnt, int* __restrict__ bbase,
    int* __restrict__ gcur, const float* __restrict__ x,
    const unsigned short* __restrict__ W1T,
    unsigned short* __restrict__ support) {
  if (blockIdx.x == 0) {
    __shared__ int ssc[512];
    const int t = threadIdx.x;
    int c0 = (t < NBUCK) ? bcnt[t] : 0;
    int c1 = (t + 256 < NBUCK) ? bcnt[t + 256] : 0;
    ssc[t] = c0; ssc[t + 256] = c1;
    __syncthreads();
#pragma unroll
    for (int off = 1; off < 512; off <<= 1) {
      int v0 = (t >= off) ? ssc[t - off] : 0;
      int v1 = ssc[t + 256 - off];
      __syncthreads();
      ssc[t] += v0; ssc[t + 256] += v1;
      __syncthreads();
    }
    if (t < NBUCK) { int e = ssc[t] - c0; bbase[t] = e; gcur[t] = e; }
    if (t + 256 < NBUCK) {
      int e = ssc[t + 256] - c1; bbase[t + 256] = e; gcur[t + 256] = e;
    }
    if (t == 0) bbase[NBUCK] = N_EDGES;
  } else {
    gemm1_body(blockIdx.x - 1, x, W1T, support);
  }
}

// ---------------------------------------------------------------------------
// K3: partition edges into bucket-contiguous regions of eb[] with
// block-level LDS counting sort -> coalesced global writes (runs ~10 edges).
// Record: uint2 { col | bf16(val)<<16 , row }.
// ---------------------------------------------------------------------------
__global__ __launch_bounds__(256) void partition_kernel(
    const int* __restrict__ erow, const int* __restrict__ ecol,
    const float* __restrict__ evals, int* __restrict__ gcur,
    uint2* __restrict__ eb) {
  __shared__ uint2 sorted[PART_T];   // 32 KB
  __shared__ int cnt[NBUCK];
  __shared__ int shift[NBUCK];
  __shared__ int ssc[512];
  const int t = threadIdx.x;
  const int base = blockIdx.x * PART_T;

  if (t < NBUCK) cnt[t] = 0;
  if (t + 256 < NBUCK) cnt[t + 256] = 0;
  __syncthreads();

  uint2 er[16];
  unsigned short loc[16];
#pragma unroll
  for (int k = 0; k < 16; k++) {
    int idx = base + k * 256 + t;
    if (idx < N_EDGES) {
      int r = erow[idx];
      er[k].y = (unsigned)r;
      er[k].x = (unsigned)ecol[idx] | ((unsigned)f2bu(evals[idx]) << 16);
      loc[k] = (unsigned short)atomicAdd(&cnt[r >> 7], 1);
    } else {
      er[k].y = 0xffffffffu;
    }
  }
  __syncthreads();

  // inclusive scan of cnt (padded to 512)
  ssc[t] = (t < NBUCK) ? cnt[t] : 0;
  ssc[t + 256] = (t + 256 < NBUCK) ? cnt[t + 256] : 0;
  __syncthreads();
#pragma unroll
  for (int off = 1; off < 512; off <<= 1) {
    int v0 = (t >= off) ? ssc[t - off] : 0;
    int v1 = ssc[t + 256 - off];
    __syncthreads();
    ssc[t] += v0; ssc[t + 256] += v1;
    __syncthreads();
  }

  // claim global region chunk per touched bucket
  for (int b = t; b < NBUCK; b += 256) {
    int c = cnt[b];
    if (c > 0) {
      int lb = ssc[b] - c;                  // local base
      int gb = atomicAdd(&gcur[b], c);      // global base of this chunk
      shift[b] = gb - lb;
    }
  }
  // scatter into LDS by bucket (ssc/cnt stable since last barrier)
#pragma unroll
  for (int k = 0; k < 16; k++) {
    if (er[k].y != 0xffffffffu) {
      int b = (int)(er[k].y >> 7);
      sorted[ssc[b] - cnt[b] + (int)loc[k]] = er[k];
    }
  }
  __syncthreads();

  // coalesced copy out: consecutive i share bucket in runs of ~10
  const int total = ssc[NBUCK - 1];
  for (int i = t; i < total; i += 256) {
    uint2 e = sorted[i];
    eb[shift[e.y >> 7] + i] = e;
  }
}

// ---------------------------------------------------------------------------
// K4: exact CSR from bucketed edges. Block b owns rows [b*128, b*128+128)
// and the eb window [bbase[b], bbase[b+1]) (~16 KB). 128-bin LDS histogram
// -> scan -> rowptr; LDS-cursor scatter of pval into csr, all writes
// confined to the 16 KB window (lines fill fully in L2, no write amp).
// eb read twice but second read is an L2 hit (32 KB window).
// ---------------------------------------------------------------------------
__global__ __launch_bounds__(256) void csr_build_kernel(
    const uint2* __restrict__ eb, const int* __restrict__ bbase,
    unsigned* __restrict__ csr, int* __restrict__ rowptr) {
  __shared__ int cnt[ROWS_PER_BUCKET];
  __shared__ int sc[ROWS_PER_BUCKET];
  __shared__ int cur[ROWS_PER_BUCKET];
  const int t = threadIdx.x;
  const int b = blockIdx.x;
  if (t < ROWS_PER_BUCKET) cnt[t] = 0;
  __syncthreads();
  const int beg = bbase[b], end = bbase[b + 1];
  for (int j = beg + t; j < end; j += 256)
    atomicAdd(&cnt[eb[j].y & 127u], 1);
  __syncthreads();
  if (t < ROWS_PER_BUCKET) sc[t] = cnt[t];
  __syncthreads();
#pragma unroll
  for (int off = 1; off < ROWS_PER_BUCKET; off <<= 1) {
    int v = 0;
    if (t >= off && t < ROWS_PER_BUCKET) v = sc[t - off];
    __syncthreads();
    if (t < ROWS_PER_BUCKET) sc[t] += v;
    __syncthreads();
  }
  if (t < ROWS_PER_BUCKET) {
    int excl = sc[t] - cnt[t];
    cur[t] = excl;
    int row = b * ROWS_PER_BUCKET + t;
    if (row < N_NODES) rowptr[row] = beg + excl;
    if (row == N_NODES - 1) rowptr[N_NODES] = N_EDGES;
  }
  __syncthreads();
  for (int j = beg + t; j < end; j += 256) {
    uint2 e = eb[j];
    int p = atomicAdd(&cur[e.y & 127u], 1);
    csr[beg + p] = e.x;
  }
}

// ---------------------------------------------------------------------------
// SpMM1 fused (round-0 structure, 8 edges in flight): wave per row, lane
// owns cols (2l,2l+1), wave-uniform edge index -> scalar csr loads + scalar
// gather bases. h[row] = bf16(dropout(relu(sum val*support[col] + b1)))
// ---------------------------------------------------------------------------
__global__ __launch_bounds__(256) void spmm1_fused(
    const unsigned* __restrict__ csr, const int* __restrict__ rowptr,
    const unsigned* __restrict__ sup,  // support rows = 64 uints (bf162)
    const float* __restrict__ b1, unsigned* __restrict__ h) {
  const int row = blockIdx.x * 4 + (threadIdx.x >> 6);
  const int lane = threadIdx.x & 63;
  const int beg = rowptr[row], end = rowptr[row + 1];
  float ax = 0.f, ay = 0.f;
  int j = beg;
  for (; j + 7 < end; j += 8) {
    unsigned p0 = csr[j],     p1 = csr[j + 1], p2 = csr[j + 2], p3 = csr[j + 3];
    unsigned p4 = csr[j + 4], p5 = csr[j + 5], p6 = csr[j + 6], p7 = csr[j + 7];
    unsigned u0 = sup[(p0 & 0xffffu) * 64 + lane];
    unsigned u1 = sup[(p1 & 0xffffu) * 64 + lane];
    unsigned u2 = sup[(p2 & 0xffffu) * 64 + lane];
    unsigned u3 = sup[(p3 & 0xffffu) * 64 + lane];
    unsigned u4 = sup[(p4 & 0xffffu) * 64 + lane];
    unsigned u5 = sup[(p5 & 0xffffu) * 64 + lane];
    unsigned u6 = sup[(p6 & 0xffffu) * 64 + lane];
    unsigned u7 = sup[(p7 & 0xffffu) * 64 + lane];
    float v0 = __uint_as_float(p0 & 0xffff0000u);
    float v1 = __uint_as_float(p1 & 0xffff0000u);
    float v2 = __uint_as_float(p2 & 0xffff0000u);
    float v3 = __uint_as_float(p3 & 0xffff0000u);
    float v4 = __uint_as_float(p4 & 0xffff0000u);
    float v5 = __uint_as_float(p5 & 0xffff0000u);
    float v6 = __uint_as_float(p6 & 0xffff0000u);
    float v7 = __uint_as_float(p7 & 0xffff0000u);
    ax += v0 * __uint_as_float(u0 << 16) + v1 * __uint_as_float(u1 << 16) +
          v2 * __uint_as_float(u2 << 16) + v3 * __uint_as_float(u3 << 16) +
          v4 * __uint_as_float(u4 << 16) + v5 * __uint_as_float(u5 << 16) +
          v6 * __uint_as_float(u6 << 16) + v7 * __uint_as_float(u7 << 16);
    ay += v0 * __uint_as_float(u0 & 0xffff0000u) +
          v1 * __uint_as_float(u1 & 0xffff0000u) +
          v2 * __uint_as_float(u2 & 0xffff0000u) +
          v3 * __uint_as_float(u3 & 0xffff0000u) +
          v4 * __uint_as_float(u4 & 0xffff0000u) +
          v5 * __uint_as_float(u5 & 0xffff0000u) +
          v6 * __uint_as_float(u6 & 0xffff0000u) +
          v7 * __uint_as_float(u7 & 0xffff0000u);
  }
  for (; j + 1 < end; j += 2) {
    unsigned p0 = csr[j], p1 = csr[j + 1];
    unsigned u0 = sup[(p0 & 0xffffu) * 64 + lane];
    unsigned u1 = sup[(p1 & 0xffffu) * 64 + lane];
    float v0 = __uint_as_float(p0 & 0xffff0000u);
    float v1 = __uint_as_float(p1 & 0xffff0000u);
    ax += v0 * __uint_as_float(u0 << 16) + v1 * __uint_as_float(u1 << 16);
    ay += v0 * __uint_as_float(u0 & 0xffff0000u) +
          v1 * __uint_as_float(u1 & 0xffff0000u);
  }
  if (j < end) {
    unsigned p0 = csr[j];
    unsigned u0 = sup[(p0 & 0xffffu) * 64 + lane];
    float v0 = __uint_as_float(p0 & 0xffff0000u);
    ax += v0 * __uint_as_float(u0 << 16);
    ay += v0 * __uint_as_float(u0 & 0xffff0000u);
  }
  const unsigned i0 = (unsigned)row * HIDDEN + lane * 2;
  float vx = fmaxf(ax + b1[lane * 2], 0.f);
  float vy = fmaxf(ay + b1[lane * 2 + 1], 0.f);
  vx = (threefry_bits(i0) >> 31) ? 0.f : 2.f * vx;
  vy = (threefry_bits(i0 + 1) >> 31) ? 0.f : 2.f * vy;
  h[(unsigned)row * 64 + lane] = (unsigned)f2bu(vx) | ((unsigned)f2bu(vy) << 16);
}

// ---------------------------------------------------------------------------
// GEMM2: h2[50000,40] = h(bf16) @ W2, fp32 compute, bf16 out. (verified)
// ---------------------------------------------------------------------------
__global__ __launch_bounds__(256) void gemm2_kernel(
    const uint4* __restrict__ h,  // rows = 16 uint4 (8 bf16 each)
    const float* __restrict__ W2, unsigned short* __restrict__ h2) {
  __shared__ float Hs[64][132];
  __shared__ float Ws[40][132];
  const int t = threadIdx.x;
  const int node_base = blockIdx.x * 64;
#pragma unroll
  for (int i = 0; i < 4; i++) {
    int lin = i * 256 + t;
    int nloc = lin >> 4, c8 = lin & 15;
    int n = node_base + nloc;
    if (n >= N_NODES) n = N_NODES - 1;
    uint4 u = h[(size_t)n * 16 + c8];
    float* d = &Hs[nloc][c8 * 8];
    d[0] = __uint_as_float(u.x << 16); d[1] = __uint_as_float(u.x & 0xffff0000u);
    d[2] = __uint_as_float(u.y << 16); d[3] = __uint_as_float(u.y & 0xffff0000u);
    d[4] = __uint_as_float(u.z << 16); d[5] = __uint_as_float(u.z & 0xffff0000u);
    d[6] = __uint_as_float(u.w << 16); d[7] = __uint_as_float(u.w & 0xffff0000u);
  }
#pragma unroll
  for (int i = 0; i < 20; i++) {
    int l = t + i * 256;
    int k = l / NCLASS, f = l % NCLASS;
    Ws[f][k] = W2[l];
  }
  __syncthreads();
  const int nloc = t >> 2;
  const int fb = t & 3;
  const int n = node_base + nloc;
  float acc[10];
#pragma unroll
  for (int j = 0; j < 10; j++) acc[j] = 0.f;
  for (int k = 0; k < HIDDEN; k += 4) {
    float4 a = *(const float4*)&Hs[nloc][k];
#pragma unroll
    for (int j = 0; j < 10; j++) {
      float4 wv = *(const float4*)&Ws[fb + 4 * j][k];
      acc[j] += a.x * wv.x + a.y * wv.y + a.z * wv.z + a.w * wv.w;
    }
  }
  if (n < N_NODES) {
#pragma unroll
    for (int j = 0; j < 10; j++)
      h2[(size_t)n * NCLASS + fb + 4 * j] = f2bu(acc[j]);
  }
}

// ---------------------------------------------------------------------------
// SpMM2 fused: wave per row, 4 edges in flight (half-split x 2-unroll).
// ---------------------------------------------------------------------------
__global__ __launch_bounds__(256) void spmm2_fused(
    const unsigned* __restrict__ csr, const int* __restrict__ rowptr,
    const unsigned* __restrict__ h2u,  // rows = 20 uints
    const float* __restrict__ b2, float* __restrict__ out) {
  const int row = blockIdx.x * 4 + (threadIdx.x >> 6);
  const int lane = threadIdx.x & 63;
  const int half = lane >> 5;
  const int il = lane & 31;
  const unsigned ilc = (il < 20) ? (unsigned)il : 19u;
  const int beg = rowptr[row], end = rowptr[row + 1];
  float ax = 0.f, ay = 0.f;
  int j = beg + half;
  for (; j + 2 < end; j += 4) {
    unsigned p0 = csr[j];
    unsigned p1 = csr[j + 2];
    unsigned u0 = h2u[(p0 & 0xffffu) * 20 + ilc];
    unsigned u1 = h2u[(p1 & 0xffffu) * 20 + ilc];
    float v0 = __uint_as_float(p0 & 0xffff0000u);
    float v1 = __uint_as_float(p1 & 0xffff0000u);
    ax += v0 * __uint_as_float(u0 << 16) + v1 * __uint_as_float(u1 << 16);
    ay += v0 * __uint_as_float(u0 & 0xffff0000u) +
          v1 * __uint_as_float(u1 & 0xffff0000u);
  }
  for (; j < end; j += 2) {
    unsigned p0 = csr[j];
    unsigned u0 = h2u[(p0 & 0xffffu) * 20 + ilc];
    float v0 = __uint_as_float(p0 & 0xffff0000u);
    ax += v0 * __uint_as_float(u0 << 16);
    ay += v0 * __uint_as_float(u0 & 0xffff0000u);
  }
  ax += __shfl_xor(ax, 32);
  ay += __shfl_xor(ay, 32);
  if (half == 0 && il < 20) {
    float2 r;
    r.x = fmaxf(ax + b2[il * 2], 0.f);
    r.y = fmaxf(ay + b2[il * 2 + 1], 0.f);
    *(float2*)&out[(unsigned)row * NCLASS + il * 2] = r;
  }
}

extern "C" void kernel_launch(void* const* d_in, const int* in_sizes, int n_in,
                              void* d_out, int out_size, void* d_ws,
                              size_t ws_size, hipStream_t stream) {
  const float* x     = (const float*)d_in[0];
  const int*   erow  = (const int*)d_in[1];
  const int*   ecol  = (const int*)d_in[2];
  const float* evals = (const float*)d_in[3];
  const float* W1    = (const float*)d_in[4];
  const float* b1    = (const float*)d_in[5];
  const float* W2    = (const float*)d_in[6];
  const float* b2    = (const float*)d_in[7];
  float* out = (float*)d_out;

  // ws layout (bytes): support 12.8M | eb/h 12.8M (h reuses eb: eb dead
  // after csr_build, h written in spmm1) | h2 4M | W1T 128K | csr 6.4M |
  // rowptr 200K | bcnt/bbase/gcur ~5K   (~36.3 MB)
  char* base = (char*)d_ws;
  unsigned short* support = (unsigned short*)base;
  uint2*          eb  = (uint2*)(base + 12800000);
  unsigned*       h   = (unsigned*)(base + 12800000);   // aliases eb
  unsigned short* h2  = (unsigned short*)(base + 25600000);
  unsigned short* W1T = (unsigned short*)(base + 29600000);
  unsigned*       csr = (unsigned*)(base + 29731072);
  int* rowptr = (int*)(base + 36131072);
  int* bcnt   = rowptr + (N_NODES + 4);
  int* bbase  = bcnt + 400;
  int* gcur   = bbase + 400;

  hipMemsetAsync(bcnt, 0, NBUCK * sizeof(int), stream);

  hist_w1t_kernel<<<HISTB + W1T_BLOCKS, 256, 0, stream>>>(erow, bcnt, W1, W1T);
  scan_gemm1_kernel<<<1 + GEMM1_BLOCKS, 256, 0, stream>>>(
      bcnt, bbase, gcur, x, W1T, support);
  partition_kernel<<<PART_BLOCKS, 256, 0, stream>>>(erow, ecol, evals, gcur,
                                                    eb);
  csr_build_kernel<<<NBUCK, 256, 0, stream>>>(eb, bbase, csr, rowptr);
  spmm1_fused<<<N_NODES / 4, 256, 0, stream>>>(csr, rowptr,
                                               (const unsigned*)support, b1, h);
  gemm2_kernel<<<(N_NODES + 63) / 64, 256, 0, stream>>>((const uint4*)h, W2,
                                                        h2);
  spmm2_fused<<<N_NODES / 4, 256, 0, stream>>>(csr, rowptr,
                                               (const unsigned*)h2, b2, out);
}

// Round 4
// 349.542 us; speedup vs baseline: 5.8529x; 1.0453x over previous
//
#include <hip/hip_runtime.h>
#include <hip/hip_bf16.h>

#define N_NODES 50000
#define N_EDGES 1600000
#define NFEAT   512
#define HIDDEN  128
#define NCLASS  40

// 128 rows per bucket -> 391 buckets; bucket id = row >> 7
#define NBUCK 391
#define ROWS_PER_BUCKET 128

#define HISTB 782                 // ceil(1600000 / 2048) edges-hist blocks
#define W1T_BLOCKS 256
#define GEMM1_BLOCKS 391          // ceil(50000/128)
#define PART_T 4096
#define PART_BLOCKS 391           // ceil(1600000/4096)

typedef short short8 __attribute__((ext_vector_type(8)));
typedef float f32x4  __attribute__((ext_vector_type(4)));

// bf16 bits (RNE) from float
__device__ __forceinline__ unsigned short f2bu(float f) {
  __hip_bfloat16 h = __float2bfloat16(f);
  return *reinterpret_cast<unsigned short*>(&h);
}

// ---------------------------------------------------------------------------
// JAX threefry2x32, key (0,42), partitionable: bits[i] = o0^o1 of ctr (0,i).
// keep iff (bits>>31)==0.  (verified in earlier rounds)
// ---------------------------------------------------------------------------
__device__ __forceinline__ unsigned rotl32(unsigned x, int n) {
  return (x << n) | (x >> (32 - n));
}

__device__ __forceinline__ unsigned threefry_bits(unsigned x1) {
  unsigned x0 = 0u;
  const unsigned ks0 = 0u, ks1 = 42u, ks2 = 0x1BD11BDAu ^ 42u;
  x0 += ks0; x1 += ks1;
#define TFR(r) { x0 += x1; x1 = rotl32(x1, (r)); x1 ^= x0; }
  TFR(13) TFR(15) TFR(26) TFR(6)
  x0 += ks1; x1 += ks2 + 1u;
  TFR(17) TFR(29) TFR(16) TFR(24)
  x0 += ks2; x1 += ks0 + 2u;
  TFR(13) TFR(15) TFR(26) TFR(6)
  x0 += ks0; x1 += ks1 + 3u;
  TFR(17) TFR(29) TFR(16) TFR(24)
  x0 += ks1; x1 += ks2 + 4u;
  TFR(13) TFR(15) TFR(26) TFR(6)
  x0 += ks2; x1 += ks0 + 5u;
#undef TFR
  return x0 ^ x1;
}

// ---------------------------------------------------------------------------
// K1 fused: 391-bin bucket histogram (blocks 0..781) | W1 transpose
// (blocks 782..1037). LDS-reduced histogram: ~391 global atomics per block.
// ---------------------------------------------------------------------------
__global__ __launch_bounds__(256) void hist_w1t_kernel(
    const int* __restrict__ erow, int* __restrict__ bcnt,
    const float* __restrict__ W1, unsigned short* __restrict__ W1T) {
  if (blockIdx.x < HISTB) {
    __shared__ int lcnt[NBUCK];
    const int t = threadIdx.x;
    if (t < NBUCK) lcnt[t] = 0;
    if (t + 256 < NBUCK) lcnt[t + 256] = 0;
    __syncthreads();
    const int base = blockIdx.x * 2048;
#pragma unroll
    for (int k = 0; k < 8; k++) {
      int idx = base + k * 256 + t;
      if (idx < N_EDGES) atomicAdd(&lcnt[erow[idx] >> 7], 1);
    }
    __syncthreads();
    if (t < NBUCK && lcnt[t]) atomicAdd(&bcnt[t], lcnt[t]);
    if (t + 256 < NBUCK && lcnt[t + 256])
      atomicAdd(&bcnt[t + 256], lcnt[t + 256]);
  } else {
    int id = (blockIdx.x - HISTB) * 256 + threadIdx.x;  // 65536 exact
    int n = id & 127, k = id >> 7;
    W1T[n * NFEAT + k] = f2bu(W1[k * HIDDEN + n]);
  }
}

// ---------------------------------------------------------------------------
// K2: 391-entry exclusive scan -> bbase, init gcur. 1 block, ~3 us.
// Split out of the GEMM1 launch so partition doesn't wait on GEMM1.
// ---------------------------------------------------------------------------
__global__ __launch_bounds__(256) void scan_kernel(
    const int* __restrict__ bcnt, int* __restrict__ bbase,
    int* __restrict__ gcur) {
  __shared__ int ssc[512];
  const int t = threadIdx.x;
  int c0 = (t < NBUCK) ? bcnt[t] : 0;
  int c1 = (t + 256 < NBUCK) ? bcnt[t + 256] : 0;
  ssc[t] = c0; ssc[t + 256] = c1;
  __syncthreads();
#pragma unroll
  for (int off = 1; off < 512; off <<= 1) {
    int v0 = (t >= off) ? ssc[t - off] : 0;
    int v1 = ssc[t + 256 - off];
    __syncthreads();
    ssc[t] += v0; ssc[t + 256] += v1;
    __syncthreads();
  }
  if (t < NBUCK) { int e = ssc[t] - c0; bbase[t] = e; gcur[t] = e; }
  if (t + 256 < NBUCK) {
    int e = ssc[t + 256] - c1; bbase[t + 256] = e; gcur[t + 256] = e;
  }
  if (t == 0) bbase[NBUCK] = N_EDGES;
}

// ---------------------------------------------------------------------------
// GEMM1 body (device fn): support = bf16(x) @ bf16(W1), fp32 acc, MFMA.
// (verified in earlier rounds, unchanged)
// ---------------------------------------------------------------------------
__device__ __forceinline__ void gemm1_body(
    int bid, const float* __restrict__ x,
    const unsigned short* __restrict__ W1T,
    unsigned short* __restrict__ support) {
  __shared__ short8 As[512];  // chunk = q*128 + row
  __shared__ short8 Bs[512];  // chunk = q*128 + col
  const int t = threadIdx.x;
  const int lane = t & 63;
  const int w = t >> 6;
  const int quad = lane >> 4;
  const int l15 = lane & 15;
  const int node_base = bid * 128;
  const int mbase = (w >> 1) * 64;
  const int nbase = (w & 1) * 64;

  f32x4 acc[4][4] = {};

  for (int k0 = 0; k0 < NFEAT; k0 += 32) {
#pragma unroll
    for (int i = 0; i < 2; i++) {
      int lin = i * 256 + t;        // 0..511
      int n = lin >> 2, q = lin & 3;
      int row = node_base + n;
      if (row >= N_NODES) row = N_NODES - 1;
      const float* src = &x[(size_t)row * NFEAT + k0 + q * 8];
      float4 a = *(const float4*)src;
      float4 b = *(const float4*)(src + 4);
      short8 p;
      p[0] = (short)f2bu(a.x); p[1] = (short)f2bu(a.y);
      p[2] = (short)f2bu(a.z); p[3] = (short)f2bu(a.w);
      p[4] = (short)f2bu(b.x); p[5] = (short)f2bu(b.y);
      p[6] = (short)f2bu(b.z); p[7] = (short)f2bu(b.w);
      As[q * 128 + n] = p;
      Bs[q * 128 + n] = *(const short8*)&W1T[(size_t)n * NFEAT + k0 + q * 8];
    }
    __syncthreads();
    short8 af[4], bfr[4];
#pragma unroll
    for (int mt = 0; mt < 4; mt++)
      af[mt] = As[quad * 128 + mbase + mt * 16 + l15];
#pragma unroll
    for (int nt = 0; nt < 4; nt++)
      bfr[nt] = Bs[quad * 128 + nbase + nt * 16 + l15];
#pragma unroll
    for (int mt = 0; mt < 4; mt++)
#pragma unroll
      for (int nt = 0; nt < 4; nt++)
        acc[mt][nt] = __builtin_amdgcn_mfma_f32_16x16x32_bf16(
            af[mt], bfr[nt], acc[mt][nt], 0, 0, 0);
    __syncthreads();
  }

#pragma unroll
  for (int mt = 0; mt < 4; mt++)
#pragma unroll
    for (int nt = 0; nt < 4; nt++)
#pragma unroll
      for (int r = 0; r < 4; r++) {
        int row = node_base + mbase + mt * 16 + quad * 4 + r;
        int col = nbase + nt * 16 + l15;
        if (row < N_NODES)
          support[(size_t)row * HIDDEN + col] = f2bu(acc[mt][nt][r]);
      }
}

// ---------------------------------------------------------------------------
// Partition body: block-level LDS counting sort of 4096 edges by bucket ->
// coalesced global writes into bucket-contiguous regions of eb[].
// Record: uint2 { col | bf16(val)<<16 , row }.
// ---------------------------------------------------------------------------
__device__ __forceinline__ void partition_body(
    int bid, const int* __restrict__ erow, const int* __restrict__ ecol,
    const float* __restrict__ evals, int* __restrict__ gcur,
    uint2* __restrict__ eb) {
  __shared__ uint2 sorted[PART_T];   // 32 KB
  __shared__ int cnt[NBUCK];
  __shared__ int shift[NBUCK];
  __shared__ int ssc[512];
  const int t = threadIdx.x;
  const int base = bid * PART_T;

  if (t < NBUCK) cnt[t] = 0;
  if (t + 256 < NBUCK) cnt[t + 256] = 0;
  __syncthreads();

  uint2 er[16];
  unsigned short loc[16];
#pragma unroll
  for (int k = 0; k < 16; k++) {
    int idx = base + k * 256 + t;
    if (idx < N_EDGES) {
      int r = erow[idx];
      er[k].y = (unsigned)r;
      er[k].x = (unsigned)ecol[idx] | ((unsigned)f2bu(evals[idx]) << 16);
      loc[k] = (unsigned short)atomicAdd(&cnt[r >> 7], 1);
    } else {
      er[k].y = 0xffffffffu;
    }
  }
  __syncthreads();

  // inclusive scan of cnt (padded to 512)
  ssc[t] = (t < NBUCK) ? cnt[t] : 0;
  ssc[t + 256] = (t + 256 < NBUCK) ? cnt[t + 256] : 0;
  __syncthreads();
#pragma unroll
  for (int off = 1; off < 512; off <<= 1) {
    int v0 = (t >= off) ? ssc[t - off] : 0;
    int v1 = ssc[t + 256 - off];
    __syncthreads();
    ssc[t] += v0; ssc[t + 256] += v1;
    __syncthreads();
  }

  // claim global region chunk per touched bucket
  for (int b = t; b < NBUCK; b += 256) {
    int c = cnt[b];
    if (c > 0) {
      int lb = ssc[b] - c;                  // local base
      int gb = atomicAdd(&gcur[b], c);      // global base of this chunk
      shift[b] = gb - lb;
    }
  }
  // scatter into LDS by bucket (ssc/cnt stable since last barrier)
#pragma unroll
  for (int k = 0; k < 16; k++) {
    if (er[k].y != 0xffffffffu) {
      int b = (int)(er[k].y >> 7);
      sorted[ssc[b] - cnt[b] + (int)loc[k]] = er[k];
    }
  }
  __syncthreads();

  // coalesced copy out: consecutive i share bucket in runs of ~10
  const int total = ssc[NBUCK - 1];
  for (int i = t; i < total; i += 256) {
    uint2 e = sorted[i];
    eb[shift[e.y >> 7] + i] = e;
  }
}

// ---------------------------------------------------------------------------
// K3 fused: partition (blocks 0..390) | GEMM1 (blocks 391..781).
// Both depend only on scan/W1T; memory-bound partition overlaps MFMA-bound
// GEMM1 on complementary pipes.
// ---------------------------------------------------------------------------
__global__ __launch_bounds__(256) void part_gemm1_kernel(
    const int* __restrict__ erow, const int* __restrict__ ecol,
    const float* __restrict__ evals, int* __restrict__ gcur,
    uint2* __restrict__ eb, const float* __restrict__ x,
    const unsigned short* __restrict__ W1T,
    unsigned short* __restrict__ support) {
  if (blockIdx.x < PART_BLOCKS)
    partition_body(blockIdx.x, erow, ecol, evals, gcur, eb);
  else
    gemm1_body(blockIdx.x - PART_BLOCKS, x, W1T, support);
}

// ---------------------------------------------------------------------------
// K4: exact CSR from bucketed edges. Block b owns rows [b*128, b*128+128)
// and the eb window [bbase[b], bbase[b+1]) (~16 KB). 128-bin LDS histogram
// -> scan -> rowptr; LDS-cursor scatter into csr, all writes confined to
// the 16 KB window. 512 threads (8 waves) for latency hiding.
// ---------------------------------------------------------------------------
__global__ __launch_bounds__(512) void csr_build_kernel(
    const uint2* __restrict__ eb, const int* __restrict__ bbase,
    unsigned* __restrict__ csr, int* __restrict__ rowptr) {
  __shared__ int cnt[ROWS_PER_BUCKET];
  __shared__ int sc[ROWS_PER_BUCKET];
  __shared__ int cur[ROWS_PER_BUCKET];
  const int t = threadIdx.x;
  const int b = blockIdx.x;
  if (t < ROWS_PER_BUCKET) cnt[t] = 0;
  __syncthreads();
  const int beg = bbase[b], end = bbase[b + 1];
  for (int j = beg + t; j < end; j += 512)
    atomicAdd(&cnt[eb[j].y & 127u], 1);
  __syncthreads();
  if (t < ROWS_PER_BUCKET) sc[t] = cnt[t];
  __syncthreads();
#pragma unroll
  for (int off = 1; off < ROWS_PER_BUCKET; off <<= 1) {
    int v = 0;
    if (t >= off && t < ROWS_PER_BUCKET) v = sc[t - off];
    __syncthreads();
    if (t < ROWS_PER_BUCKET) sc[t] += v;
    __syncthreads();
  }
  if (t < ROWS_PER_BUCKET) {
    int excl = sc[t] - cnt[t];
    cur[t] = excl;
    int row = b * ROWS_PER_BUCKET + t;
    if (row < N_NODES) rowptr[row] = beg + excl;
    if (row == N_NODES - 1) rowptr[N_NODES] = N_EDGES;
  }
  __syncthreads();
  for (int j = beg + t; j < end; j += 512) {
    uint2 e = eb[j];
    int p = atomicAdd(&cur[e.y & 127u], 1);
    csr[beg + p] = e.x;
  }
}

// ---------------------------------------------------------------------------
// SpMM1 fused: wave per row, 16 edges in flight (gather is latency-bound on
// L2/L3-resident support; deeper MLP hides it). Lane owns cols (2l,2l+1).
// h[row] = bf16(dropout(relu(sum val*support[col] + b1)))
// ---------------------------------------------------------------------------
__global__ __launch_bounds__(256) void spmm1_fused(
    const unsigned* __restrict__ csr, const int* __restrict__ rowptr,
    const unsigned* __restrict__ sup,  // support rows = 64 uints (bf162)
    const float* __restrict__ b1, unsigned* __restrict__ h) {
  const int row = blockIdx.x * 4 + (threadIdx.x >> 6);
  const int lane = threadIdx.x & 63;
  const int beg = rowptr[row], end = rowptr[row + 1];
  float ax = 0.f, ay = 0.f;
  int j = beg;
  for (; j + 15 < end; j += 16) {
    unsigned p[16], u[16];
#pragma unroll
    for (int k = 0; k < 16; k++) p[k] = csr[j + k];
#pragma unroll
    for (int k = 0; k < 16; k++) u[k] = sup[(p[k] & 0xffffu) * 64 + lane];
#pragma unroll
    for (int k = 0; k < 16; k++) {
      float v = __uint_as_float(p[k] & 0xffff0000u);
      ax += v * __uint_as_float(u[k] << 16);
      ay += v * __uint_as_float(u[k] & 0xffff0000u);
    }
  }
  for (; j + 7 < end; j += 8) {
    unsigned p[8], u[8];
#pragma unroll
    for (int k = 0; k < 8; k++) p[k] = csr[j + k];
#pragma unroll
    for (int k = 0; k < 8; k++) u[k] = sup[(p[k] & 0xffffu) * 64 + lane];
#pragma unroll
    for (int k = 0; k < 8; k++) {
      float v = __uint_as_float(p[k] & 0xffff0000u);
      ax += v * __uint_as_float(u[k] << 16);
      ay += v * __uint_as_float(u[k] & 0xffff0000u);
    }
  }
  for (; j + 1 < end; j += 2) {
    unsigned p0 = csr[j], p1 = csr[j + 1];
    unsigned u0 = sup[(p0 & 0xffffu) * 64 + lane];
    unsigned u1 = sup[(p1 & 0xffffu) * 64 + lane];
    float v0 = __uint_as_float(p0 & 0xffff0000u);
    float v1 = __uint_as_float(p1 & 0xffff0000u);
    ax += v0 * __uint_as_float(u0 << 16) + v1 * __uint_as_float(u1 << 16);
    ay += v0 * __uint_as_float(u0 & 0xffff0000u) +
          v1 * __uint_as_float(u1 & 0xffff0000u);
  }
  if (j < end) {
    unsigned p0 = csr[j];
    unsigned u0 = sup[(p0 & 0xffffu) * 64 + lane];
    float v0 = __uint_as_float(p0 & 0xffff0000u);
    ax += v0 * __uint_as_float(u0 << 16);
    ay += v0 * __uint_as_float(u0 & 0xffff0000u);
  }
  const unsigned i0 = (unsigned)row * HIDDEN + lane * 2;
  float vx = fmaxf(ax + b1[lane * 2], 0.f);
  float vy = fmaxf(ay + b1[lane * 2 + 1], 0.f);
  vx = (threefry_bits(i0) >> 31) ? 0.f : 2.f * vx;
  vy = (threefry_bits(i0 + 1) >> 31) ? 0.f : 2.f * vy;
  h[(unsigned)row * 64 + lane] = (unsigned)f2bu(vx) | ((unsigned)f2bu(vy) << 16);
}

// ---------------------------------------------------------------------------
// GEMM2: h2[50000,40] = h(bf16) @ W2, fp32 compute, bf16 out. (verified)
// ---------------------------------------------------------------------------
__global__ __launch_bounds__(256) void gemm2_kernel(
    const uint4* __restrict__ h,  // rows = 16 uint4 (8 bf16 each)
    const float* __restrict__ W2, unsigned short* __restrict__ h2) {
  __shared__ float Hs[64][132];
  __shared__ float Ws[40][132];
  const int t = threadIdx.x;
  const int node_base = blockIdx.x * 64;
#pragma unroll
  for (int i = 0; i < 4; i++) {
    int lin = i * 256 + t;
    int nloc = lin >> 4, c8 = lin & 15;
    int n = node_base + nloc;
    if (n >= N_NODES) n = N_NODES - 1;
    uint4 u = h[(size_t)n * 16 + c8];
    float* d = &Hs[nloc][c8 * 8];
    d[0] = __uint_as_float(u.x << 16); d[1] = __uint_as_float(u.x & 0xffff0000u);
    d[2] = __uint_as_float(u.y << 16); d[3] = __uint_as_float(u.y & 0xffff0000u);
    d[4] = __uint_as_float(u.z << 16); d[5] = __uint_as_float(u.z & 0xffff0000u);
    d[6] = __uint_as_float(u.w << 16); d[7] = __uint_as_float(u.w & 0xffff0000u);
  }
#pragma unroll
  for (int i = 0; i < 20; i++) {
    int l = t + i * 256;
    int k = l / NCLASS, f = l % NCLASS;
    Ws[f][k] = W2[l];
  }
  __syncthreads();
  const int nloc = t >> 2;
  const int fb = t & 3;
  const int n = node_base + nloc;
  float acc[10];
#pragma unroll
  for (int j = 0; j < 10; j++) acc[j] = 0.f;
  for (int k = 0; k < HIDDEN; k += 4) {
    float4 a = *(const float4*)&Hs[nloc][k];
#pragma unroll
    for (int j = 0; j < 10; j++) {
      float4 wv = *(const float4*)&Ws[fb + 4 * j][k];
      acc[j] += a.x * wv.x + a.y * wv.y + a.z * wv.z + a.w * wv.w;
    }
  }
  if (n < N_NODES) {
#pragma unroll
    for (int j = 0; j < 10; j++)
      h2[(size_t)n * NCLASS + fb + 4 * j] = f2bu(acc[j]);
  }
}

// ---------------------------------------------------------------------------
// SpMM2 fused: wave per row, half-split x 4-unroll = 8 edges in flight.
// ---------------------------------------------------------------------------
__global__ __launch_bounds__(256) void spmm2_fused(
    const unsigned* __restrict__ csr, const int* __restrict__ rowptr,
    const unsigned* __restrict__ h2u,  // rows = 20 uints
    const float* __restrict__ b2, float* __restrict__ out) {
  const int row = blockIdx.x * 4 + (threadIdx.x >> 6);
  const int lane = threadIdx.x & 63;
  const int half = lane >> 5;
  const int il = lane & 31;
  const unsigned ilc = (il < 20) ? (unsigned)il : 19u;
  const int beg = rowptr[row], end = rowptr[row + 1];
  float ax = 0.f, ay = 0.f;
  int j = beg + half;
  for (; j + 6 < end; j += 8) {
    unsigned p[4], u[4];
#pragma unroll
    for (int k = 0; k < 4; k++) p[k] = csr[j + 2 * k];
#pragma unroll
    for (int k = 0; k < 4; k++) u[k] = h2u[(p[k] & 0xffffu) * 20 + ilc];
#pragma unroll
    for (int k = 0; k < 4; k++) {
      float v = __uint_as_float(p[k] & 0xffff0000u);
      ax += v * __uint_as_float(u[k] << 16);
      ay += v * __uint_as_float(u[k] & 0xffff0000u);
    }
  }
  for (; j + 2 < end; j += 4) {
    unsigned p0 = csr[j];
    unsigned p1 = csr[j + 2];
    unsigned u0 = h2u[(p0 & 0xffffu) * 20 + ilc];
    unsigned u1 = h2u[(p1 & 0xffffu) * 20 + ilc];
    float v0 = __uint_as_float(p0 & 0xffff0000u);
    float v1 = __uint_as_float(p1 & 0xffff0000u);
    ax += v0 * __uint_as_float(u0 << 16) + v1 * __uint_as_float(u1 << 16);
    ay += v0 * __uint_as_float(u0 & 0xffff0000u) +
          v1 * __uint_as_float(u1 & 0xffff0000u);
  }
  for (; j < end; j += 2) {
    unsigned p0 = csr[j];
    unsigned u0 = h2u[(p0 & 0xffffu) * 20 + ilc];
    float v0 = __uint_as_float(p0 & 0xffff0000u);
    ax += v0 * __uint_as_float(u0 << 16);
    ay += v0 * __uint_as_float(u0 & 0xffff0000u);
  }
  ax += __shfl_xor(ax, 32);
  ay += __shfl_xor(ay, 32);
  if (half == 0 && il < 20) {
    float2 r;
    r.x = fmaxf(ax + b2[il * 2], 0.f);
    r.y = fmaxf(ay + b2[il * 2 + 1], 0.f);
    *(float2*)&out[(unsigned)row * NCLASS + il * 2] = r;
  }
}

extern "C" void kernel_launch(void* const* d_in, const int* in_sizes, int n_in,
                              void* d_out, int out_size, void* d_ws,
                              size_t ws_size, hipStream_t stream) {
  const float* x     = (const float*)d_in[0];
  const int*   erow  = (const int*)d_in[1];
  const int*   ecol  = (const int*)d_in[2];
  const float* evals = (const float*)d_in[3];
  const float* W1    = (const float*)d_in[4];
  const float* b1    = (const float*)d_in[5];
  const float* W2    = (const float*)d_in[6];
  const float* b2    = (const float*)d_in[7];
  float* out = (float*)d_out;

  // ws layout (bytes): support 12.8M | eb/h 12.8M (h reuses eb: eb dead
  // after csr_build, h written in spmm1) | h2 4M | W1T 128K | csr 6.4M |
  // rowptr 200K | bcnt/bbase/gcur ~5K   (~36.3 MB)
  char* base = (char*)d_ws;
  unsigned short* support = (unsigned short*)base;
  uint2*          eb  = (uint2*)(base + 12800000);
  unsigned*       h   = (unsigned*)(base + 12800000);   // aliases eb
  unsigned short* h2  = (unsigned short*)(base + 25600000);
  unsigned short* W1T = (unsigned short*)(base + 29600000);
  unsigned*       csr = (unsigned*)(base + 29731072);
  int* rowptr = (int*)(base + 36131072);
  int* bcnt   = rowptr + (N_NODES + 4);
  int* bbase  = bcnt + 400;
  int* gcur   = bbase + 400;

  hipMemsetAsync(bcnt, 0, NBUCK * sizeof(int), stream);

  hist_w1t_kernel<<<HISTB + W1T_BLOCKS, 256, 0, stream>>>(erow, bcnt, W1, W1T);
  scan_kernel<<<1, 256, 0, stream>>>(bcnt, bbase, gcur);
  part_gemm1_kernel<<<PART_BLOCKS + GEMM1_BLOCKS, 256, 0, stream>>>(
      erow, ecol, evals, gcur, eb, x, W1T, support);
  csr_build_kernel<<<NBUCK, 512, 0, stream>>>(eb, bbase, csr, rowptr);
  spmm1_fused<<<N_NODES / 4, 256, 0, stream>>>(csr, rowptr,
                                               (const unsigned*)support, b1, h);
  gemm2_kernel<<<(N_NODES + 63) / 64, 256, 0, stream>>>((const uint4*)h, W2,
                                                        h2);
  spmm2_fused<<<N_NODES / 4, 256, 0, stream>>>(csr, rowptr,
                                               (const unsigned*)h2, b2, out);
}

// Round 5
// 331.067 us; speedup vs baseline: 6.1796x; 1.0558x over previous
//
#include <hip/hip_runtime.h>
#include <hip/hip_bf16.h>

#define N_NODES 50000
#define N_EDGES 1600000
#define NFEAT   512
#define HIDDEN  128
#define NCLASS  40

// 128 rows per bucket -> 391 buckets; bucket id = row >> 7
#define NBUCK 391
#define ROWS_PER_BUCKET 128
#define BUCK_PAD 4608             // mean 4096 + 8 sigma; padded bucket slots

#define W1T_BLOCKS 256
#define GEMM1_BLOCKS 391          // ceil(50000/128)
#define PART_T 2048
#define PART_BLOCKS 782           // ceil(1600000/2048)

// union LDS for the fused partition|gemm1 kernel:
// partition: sorted 16384 | cnt 1564 | shift 1564 | ssc 2048 = 21560
// gemm1:     As 8192 | Bs 8192 = 16384          -> max = 21560
#define FUSED_LDS 21560

typedef short short8 __attribute__((ext_vector_type(8)));
typedef float f32x4  __attribute__((ext_vector_type(4)));

// bf16 bits (RNE) from float
__device__ __forceinline__ unsigned short f2bu(float f) {
  __hip_bfloat16 h = __float2bfloat16(f);
  return *reinterpret_cast<unsigned short*>(&h);
}

// ---------------------------------------------------------------------------
// JAX threefry2x32, key (0,42), partitionable: bits[i] = o0^o1 of ctr (0,i).
// keep iff (bits>>31)==0.  (verified in earlier rounds)
// ---------------------------------------------------------------------------
__device__ __forceinline__ unsigned rotl32(unsigned x, int n) {
  return (x << n) | (x >> (32 - n));
}

__device__ __forceinline__ unsigned threefry_bits(unsigned x1) {
  unsigned x0 = 0u;
  const unsigned ks0 = 0u, ks1 = 42u, ks2 = 0x1BD11BDAu ^ 42u;
  x0 += ks0; x1 += ks1;
#define TFR(r) { x0 += x1; x1 = rotl32(x1, (r)); x1 ^= x0; }
  TFR(13) TFR(15) TFR(26) TFR(6)
  x0 += ks1; x1 += ks2 + 1u;
  TFR(17) TFR(29) TFR(16) TFR(24)
  x0 += ks2; x1 += ks0 + 2u;
  TFR(13) TFR(15) TFR(26) TFR(6)
  x0 += ks0; x1 += ks1 + 3u;
  TFR(17) TFR(29) TFR(16) TFR(24)
  x0 += ks1; x1 += ks2 + 4u;
  TFR(13) TFR(15) TFR(26) TFR(6)
  x0 += ks2; x1 += ks0 + 5u;
#undef TFR
  return x0 ^ x1;
}

// ---------------------------------------------------------------------------
// K1: W1 transpose (blocks 0..255) | gcur init to padded bucket bases
// (block 256). No histogram/scan needed with padded buckets.
// ---------------------------------------------------------------------------
__global__ __launch_bounds__(256) void init_w1t_kernel(
    const float* __restrict__ W1, unsigned short* __restrict__ W1T,
    int* __restrict__ gcur) {
  if (blockIdx.x < W1T_BLOCKS) {
    int id = blockIdx.x * 256 + threadIdx.x;  // 65536 exact
    int n = id & 127, k = id >> 7;
    W1T[n * NFEAT + k] = f2bu(W1[k * HIDDEN + n]);
  } else {
    int b = threadIdx.x;
    if (b < NBUCK) gcur[b] = b * BUCK_PAD;
    b += 256;
    if (b < NBUCK) gcur[b] = b * BUCK_PAD;
  }
}

// ---------------------------------------------------------------------------
// GEMM1 body (device fn): support = bf16(x) @ bf16(W1), fp32 acc, MFMA.
// (verified; LDS now passed in as union buffer)
// ---------------------------------------------------------------------------
__device__ __forceinline__ void gemm1_body(
    int bid, char* smem, const float* __restrict__ x,
    const unsigned short* __restrict__ W1T,
    unsigned short* __restrict__ support) {
  short8* As = (short8*)smem;           // 512 * 16 B, chunk = q*128 + row
  short8* Bs = (short8*)(smem + 8192);  // 512 * 16 B, chunk = q*128 + col
  const int t = threadIdx.x;
  const int lane = t & 63;
  const int w = t >> 6;
  const int quad = lane >> 4;
  const int l15 = lane & 15;
  const int node_base = bid * 128;
  const int mbase = (w >> 1) * 64;
  const int nbase = (w & 1) * 64;

  f32x4 acc[4][4] = {};

  for (int k0 = 0; k0 < NFEAT; k0 += 32) {
#pragma unroll
    for (int i = 0; i < 2; i++) {
      int lin = i * 256 + t;        // 0..511
      int n = lin >> 2, q = lin & 3;
      int row = node_base + n;
      if (row >= N_NODES) row = N_NODES - 1;
      const float* src = &x[(size_t)row * NFEAT + k0 + q * 8];
      float4 a = *(const float4*)src;
      float4 b = *(const float4*)(src + 4);
      short8 p;
      p[0] = (short)f2bu(a.x); p[1] = (short)f2bu(a.y);
      p[2] = (short)f2bu(a.z); p[3] = (short)f2bu(a.w);
      p[4] = (short)f2bu(b.x); p[5] = (short)f2bu(b.y);
      p[6] = (short)f2bu(b.z); p[7] = (short)f2bu(b.w);
      As[q * 128 + n] = p;
      Bs[q * 128 + n] = *(const short8*)&W1T[(size_t)n * NFEAT + k0 + q * 8];
    }
    __syncthreads();
    short8 af[4], bfr[4];
#pragma unroll
    for (int mt = 0; mt < 4; mt++)
      af[mt] = As[quad * 128 + mbase + mt * 16 + l15];
#pragma unroll
    for (int nt = 0; nt < 4; nt++)
      bfr[nt] = Bs[quad * 128 + nbase + nt * 16 + l15];
#pragma unroll
    for (int mt = 0; mt < 4; mt++)
#pragma unroll
      for (int nt = 0; nt < 4; nt++)
        acc[mt][nt] = __builtin_amdgcn_mfma_f32_16x16x32_bf16(
            af[mt], bfr[nt], acc[mt][nt], 0, 0, 0);
    __syncthreads();
  }

#pragma unroll
  for (int mt = 0; mt < 4; mt++)
#pragma unroll
    for (int nt = 0; nt < 4; nt++)
#pragma unroll
      for (int r = 0; r < 4; r++) {
        int row = node_base + mbase + mt * 16 + quad * 4 + r;
        int col = nbase + nt * 16 + l15;
        if (row < N_NODES)
          support[(size_t)row * HIDDEN + col] = f2bu(acc[mt][nt][r]);
      }
}

// ---------------------------------------------------------------------------
// Partition body: LDS counting sort of 2048 edges by bucket -> coalesced
// append into padded bucket regions of eb[] (gcur[b] starts at b*BUCK_PAD).
// Record: uint2 { col | bf16(val)<<16 , row }.
// ---------------------------------------------------------------------------
__device__ __forceinline__ void partition_body(
    int bid, char* smem, const int* __restrict__ erow,
    const int* __restrict__ ecol, const float* __restrict__ evals,
    int* __restrict__ gcur, uint2* __restrict__ eb) {
  uint2* sorted = (uint2*)smem;                  // 2048 * 8 B
  int* cnt   = (int*)(smem + 16384);             // 391 * 4
  int* shift = (int*)(smem + 16384 + 1564);      // 391 * 4
  int* ssc   = (int*)(smem + 16384 + 3128);      // 512 * 4
  const int t = threadIdx.x;
  const int base = bid * PART_T;

  if (t < NBUCK) cnt[t] = 0;
  if (t + 256 < NBUCK) cnt[t + 256] = 0;
  __syncthreads();

  uint2 er[8];
  unsigned short loc[8];
#pragma unroll
  for (int k = 0; k < 8; k++) {
    int idx = base + k * 256 + t;
    if (idx < N_EDGES) {
      int r = erow[idx];
      er[k].y = (unsigned)r;
      er[k].x = (unsigned)ecol[idx] | ((unsigned)f2bu(evals[idx]) << 16);
      loc[k] = (unsigned short)atomicAdd(&cnt[r >> 7], 1);
    } else {
      er[k].y = 0xffffffffu;
    }
  }
  __syncthreads();

  // inclusive scan of cnt (padded to 512)
  ssc[t] = (t < NBUCK) ? cnt[t] : 0;
  ssc[t + 256] = (t + 256 < NBUCK) ? cnt[t + 256] : 0;
  __syncthreads();
#pragma unroll
  for (int off = 1; off < 512; off <<= 1) {
    int v0 = (t >= off) ? ssc[t - off] : 0;
    int v1 = ssc[t + 256 - off];
    __syncthreads();
    ssc[t] += v0; ssc[t + 256] += v1;
    __syncthreads();
  }

  // claim chunk in the padded bucket region
  for (int b = t; b < NBUCK; b += 256) {
    int c = cnt[b];
    if (c > 0) {
      int lb = ssc[b] - c;                  // local base
      int gb = atomicAdd(&gcur[b], c);      // global base of this chunk
      shift[b] = gb - lb;
    }
  }
  // scatter into LDS by bucket (ssc/cnt stable since last barrier)
#pragma unroll
  for (int k = 0; k < 8; k++) {
    if (er[k].y != 0xffffffffu) {
      int b = (int)(er[k].y >> 7);
      sorted[ssc[b] - cnt[b] + (int)loc[k]] = er[k];
    }
  }
  __syncthreads();

  // coalesced copy out: consecutive i share bucket in runs of ~5
  const int total = ssc[NBUCK - 1];
  for (int i = t; i < total; i += 256) {
    uint2 e = sorted[i];
    eb[shift[e.y >> 7] + i] = e;
  }
}

// ---------------------------------------------------------------------------
// K2 fused: partition (blocks 0..781) | GEMM1 (blocks 782..1172).
// Single union LDS buffer (21.6 KB) -> 7 blocks/CU occupancy.
// ---------------------------------------------------------------------------
__global__ __launch_bounds__(256) void part_gemm1_kernel(
    const int* __restrict__ erow, const int* __restrict__ ecol,
    const float* __restrict__ evals, int* __restrict__ gcur,
    uint2* __restrict__ eb, const float* __restrict__ x,
    const unsigned short* __restrict__ W1T,
    unsigned short* __restrict__ support) {
  __shared__ char smem[FUSED_LDS];
  if (blockIdx.x < PART_BLOCKS)
    partition_body(blockIdx.x, smem, erow, ecol, evals, gcur, eb);
  else
    gemm1_body(blockIdx.x - PART_BLOCKS, smem, x, W1T, support);
}

// ---------------------------------------------------------------------------
// K3: exact CSR from padded bucketed edges. Block b owns rows
// [b*128, b*128+128) and eb window [b*BUCK_PAD, gcur[b]). 128-bin LDS
// histogram -> scan -> rowptr/rowend; LDS-cursor scatter into csr (padded
// layout, same indexing). All scattered writes land in a ~16 KB window.
// ---------------------------------------------------------------------------
__global__ __launch_bounds__(512) void csr_build_kernel(
    const uint2* __restrict__ eb, const int* __restrict__ gcur,
    unsigned* __restrict__ csr, int* __restrict__ rowptr,
    int* __restrict__ rowend) {
  __shared__ int cnt[ROWS_PER_BUCKET];
  __shared__ int sc[ROWS_PER_BUCKET];
  __shared__ int cur[ROWS_PER_BUCKET];
  const int t = threadIdx.x;
  const int b = blockIdx.x;
  if (t < ROWS_PER_BUCKET) cnt[t] = 0;
  __syncthreads();
  const int beg = b * BUCK_PAD;
  const int end = gcur[b];
  for (int j = beg + t; j < end; j += 512)
    atomicAdd(&cnt[eb[j].y & 127u], 1);
  __syncthreads();
  if (t < ROWS_PER_BUCKET) sc[t] = cnt[t];
  __syncthreads();
#pragma unroll
  for (int off = 1; off < ROWS_PER_BUCKET; off <<= 1) {
    int v = 0;
    if (t >= off && t < ROWS_PER_BUCKET) v = sc[t - off];
    __syncthreads();
    if (t < ROWS_PER_BUCKET) sc[t] += v;
    __syncthreads();
  }
  if (t < ROWS_PER_BUCKET) {
    int excl = sc[t] - cnt[t];
    cur[t] = excl;
    int row = b * ROWS_PER_BUCKET + t;
    if (row < N_NODES) {
      rowptr[row] = beg + excl;
      rowend[row] = beg + sc[t];
    }
  }
  __syncthreads();
  for (int j = beg + t; j < end; j += 512) {
    uint2 e = eb[j];
    int p = atomicAdd(&cur[e.y & 127u], 1);
    csr[beg + p] = e.x;
  }
}

// ---------------------------------------------------------------------------
// SpMM1 fused: wave per row, 16 edges in flight. Lane owns cols (2l,2l+1).
// h[row] = bf16(dropout(relu(sum val*support[col] + b1)))
// ---------------------------------------------------------------------------
__global__ __launch_bounds__(256) void spmm1_fused(
    const unsigned* __restrict__ csr, const int* __restrict__ rowptr,
    const int* __restrict__ rowend,
    const unsigned* __restrict__ sup,  // support rows = 64 uints (bf162)
    const float* __restrict__ b1, unsigned* __restrict__ h) {
  const int row = blockIdx.x * 4 + (threadIdx.x >> 6);
  const int lane = threadIdx.x & 63;
  const int beg = rowptr[row], end = rowend[row];
  float ax = 0.f, ay = 0.f;
  int j = beg;
  for (; j + 15 < end; j += 16) {
    unsigned p[16], u[16];
#pragma unroll
    for (int k = 0; k < 16; k++) p[k] = csr[j + k];
#pragma unroll
    for (int k = 0; k < 16; k++) u[k] = sup[(p[k] & 0xffffu) * 64 + lane];
#pragma unroll
    for (int k = 0; k < 16; k++) {
      float v = __uint_as_float(p[k] & 0xffff0000u);
      ax += v * __uint_as_float(u[k] << 16);
      ay += v * __uint_as_float(u[k] & 0xffff0000u);
    }
  }
  for (; j + 7 < end; j += 8) {
    unsigned p[8], u[8];
#pragma unroll
    for (int k = 0; k < 8; k++) p[k] = csr[j + k];
#pragma unroll
    for (int k = 0; k < 8; k++) u[k] = sup[(p[k] & 0xffffu) * 64 + lane];
#pragma unroll
    for (int k = 0; k < 8; k++) {
      float v = __uint_as_float(p[k] & 0xffff0000u);
      ax += v * __uint_as_float(u[k] << 16);
      ay += v * __uint_as_float(u[k] & 0xffff0000u);
    }
  }
  for (; j + 1 < end; j += 2) {
    unsigned p0 = csr[j], p1 = csr[j + 1];
    unsigned u0 = sup[(p0 & 0xffffu) * 64 + lane];
    unsigned u1 = sup[(p1 & 0xffffu) * 64 + lane];
    float v0 = __uint_as_float(p0 & 0xffff0000u);
    float v1 = __uint_as_float(p1 & 0xffff0000u);
    ax += v0 * __uint_as_float(u0 << 16) + v1 * __uint_as_float(u1 << 16);
    ay += v0 * __uint_as_float(u0 & 0xffff0000u) +
          v1 * __uint_as_float(u1 & 0xffff0000u);
  }
  if (j < end) {
    unsigned p0 = csr[j];
    unsigned u0 = sup[(p0 & 0xffffu) * 64 + lane];
    float v0 = __uint_as_float(p0 & 0xffff0000u);
    ax += v0 * __uint_as_float(u0 << 16);
    ay += v0 * __uint_as_float(u0 & 0xffff0000u);
  }
  const unsigned i0 = (unsigned)row * HIDDEN + lane * 2;
  float vx = fmaxf(ax + b1[lane * 2], 0.f);
  float vy = fmaxf(ay + b1[lane * 2 + 1], 0.f);
  vx = (threefry_bits(i0) >> 31) ? 0.f : 2.f * vx;
  vy = (threefry_bits(i0 + 1) >> 31) ? 0.f : 2.f * vy;
  h[(unsigned)row * 64 + lane] = (unsigned)f2bu(vx) | ((unsigned)f2bu(vy) << 16);
}

// ---------------------------------------------------------------------------
// GEMM2: h2[50000,40] = h(bf16) @ W2, fp32 compute, bf16 out. (verified)
// ---------------------------------------------------------------------------
__global__ __launch_bounds__(256) void gemm2_kernel(
    const uint4* __restrict__ h,  // rows = 16 uint4 (8 bf16 each)
    const float* __restrict__ W2, unsigned short* __restrict__ h2) {
  __shared__ float Hs[64][132];
  __shared__ float Ws[40][132];
  const int t = threadIdx.x;
  const int node_base = blockIdx.x * 64;
#pragma unroll
  for (int i = 0; i < 4; i++) {
    int lin = i * 256 + t;
    int nloc = lin >> 4, c8 = lin & 15;
    int n = node_base + nloc;
    if (n >= N_NODES) n = N_NODES - 1;
    uint4 u = h[(size_t)n * 16 + c8];
    float* d = &Hs[nloc][c8 * 8];
    d[0] = __uint_as_float(u.x << 16); d[1] = __uint_as_float(u.x & 0xffff0000u);
    d[2] = __uint_as_float(u.y << 16); d[3] = __uint_as_float(u.y & 0xffff0000u);
    d[4] = __uint_as_float(u.z << 16); d[5] = __uint_as_float(u.z & 0xffff0000u);
    d[6] = __uint_as_float(u.w << 16); d[7] = __uint_as_float(u.w & 0xffff0000u);
  }
#pragma unroll
  for (int i = 0; i < 20; i++) {
    int l = t + i * 256;
    int k = l / NCLASS, f = l % NCLASS;
    Ws[f][k] = W2[l];
  }
  __syncthreads();
  const int nloc = t >> 2;
  const int fb = t & 3;
  const int n = node_base + nloc;
  float acc[10];
#pragma unroll
  for (int j = 0; j < 10; j++) acc[j] = 0.f;
  for (int k = 0; k < HIDDEN; k += 4) {
    float4 a = *(const float4*)&Hs[nloc][k];
#pragma unroll
    for (int j = 0; j < 10; j++) {
      float4 wv = *(const float4*)&Ws[fb + 4 * j][k];
      acc[j] += a.x * wv.x + a.y * wv.y + a.z * wv.z + a.w * wv.w;
    }
  }
  if (n < N_NODES) {
#pragma unroll
    for (int j = 0; j < 10; j++)
      h2[(size_t)n * NCLASS + fb + 4 * j] = f2bu(acc[j]);
  }
}

// ---------------------------------------------------------------------------
// SpMM2 fused: wave per row, half-split x 4-unroll = 8 edges in flight.
// ---------------------------------------------------------------------------
__global__ __launch_bounds__(256) void spmm2_fused(
    const unsigned* __restrict__ csr, const int* __restrict__ rowptr,
    const int* __restrict__ rowend,
    const unsigned* __restrict__ h2u,  // rows = 20 uints
    const float* __restrict__ b2, float* __restrict__ out) {
  const int row = blockIdx.x * 4 + (threadIdx.x >> 6);
  const int lane = threadIdx.x & 63;
  const int half = lane >> 5;
  const int il = lane & 31;
  const unsigned ilc = (il < 20) ? (unsigned)il : 19u;
  const int beg = rowptr[row], end = rowend[row];
  float ax = 0.f, ay = 0.f;
  int j = beg + half;
  for (; j + 6 < end; j += 8) {
    unsigned p[4], u[4];
#pragma unroll
    for (int k = 0; k < 4; k++) p[k] = csr[j + 2 * k];
#pragma unroll
    for (int k = 0; k < 4; k++) u[k] = h2u[(p[k] & 0xffffu) * 20 + ilc];
#pragma unroll
    for (int k = 0; k < 4; k++) {
      float v = __uint_as_float(p[k] & 0xffff0000u);
      ax += v * __uint_as_float(u[k] << 16);
      ay += v * __uint_as_float(u[k] & 0xffff0000u);
    }
  }
  for (; j + 2 < end; j += 4) {
    unsigned p0 = csr[j];
    unsigned p1 = csr[j + 2];
    unsigned u0 = h2u[(p0 & 0xffffu) * 20 + ilc];
    unsigned u1 = h2u[(p1 & 0xffffu) * 20 + ilc];
    float v0 = __uint_as_float(p0 & 0xffff0000u);
    float v1 = __uint_as_float(p1 & 0xffff0000u);
    ax += v0 * __uint_as_float(u0 << 16) + v1 * __uint_as_float(u1 << 16);
    ay += v0 * __uint_as_float(u0 & 0xffff0000u) +
          v1 * __uint_as_float(u1 & 0xffff0000u);
  }
  for (; j < end; j += 2) {
    unsigned p0 = csr[j];
    unsigned u0 = h2u[(p0 & 0xffffu) * 20 + ilc];
    float v0 = __uint_as_float(p0 & 0xffff0000u);
    ax += v0 * __uint_as_float(u0 << 16);
    ay += v0 * __uint_as_float(u0 & 0xffff0000u);
  }
  ax += __shfl_xor(ax, 32);
  ay += __shfl_xor(ay, 32);
  if (half == 0 && il < 20) {
    float2 r;
    r.x = fmaxf(ax + b2[il * 2], 0.f);
    r.y = fmaxf(ay + b2[il * 2 + 1], 0.f);
    *(float2*)&out[(unsigned)row * NCLASS + il * 2] = r;
  }
}

extern "C" void kernel_launch(void* const* d_in, const int* in_sizes, int n_in,
                              void* d_out, int out_size, void* d_ws,
                              size_t ws_size, hipStream_t stream) {
  const float* x     = (const float*)d_in[0];
  const int*   erow  = (const int*)d_in[1];
  const int*   ecol  = (const int*)d_in[2];
  const float* evals = (const float*)d_in[3];
  const float* W1    = (const float*)d_in[4];
  const float* b1    = (const float*)d_in[5];
  const float* W2    = (const float*)d_in[6];
  const float* b2    = (const float*)d_in[7];
  float* out = (float*)d_out;

  // ws layout (bytes):
  //   support 12.8M @ 0
  //   eb (padded, 391*4608*8 = 14,413,824) @ 12,800,000; h (12.8M) aliases
  //     eb start (eb dead after csr_build, h written by spmm1)
  //   h2 4M @ 27,213,824 | W1T 128K @ 31,213,824
  //   csr (padded, 7,206,912) @ 31,344,896
  //   rowptr 200K @ 38,551,808 | rowend 200K @ 38,751,808
  //   gcur 1.6K @ 38,951,808        (~39 MB total)
  char* base = (char*)d_ws;
  unsigned short* support = (unsigned short*)base;
  uint2*          eb  = (uint2*)(base + 12800000);
  unsigned*       h   = (unsigned*)(base + 12800000);   // aliases eb
  unsigned short* h2  = (unsigned short*)(base + 27213824);
  unsigned short* W1T = (unsigned short*)(base + 31213824);
  unsigned*       csr = (unsigned*)(base + 31344896);
  int* rowptr = (int*)(base + 38551808);
  int* rowend = (int*)(base + 38751808);
  int* gcur   = (int*)(base + 38951808);

  init_w1t_kernel<<<W1T_BLOCKS + 1, 256, 0, stream>>>(W1, W1T, gcur);
  part_gemm1_kernel<<<PART_BLOCKS + GEMM1_BLOCKS, 256, 0, stream>>>(
      erow, ecol, evals, gcur, eb, x, W1T, support);
  csr_build_kernel<<<NBUCK, 512, 0, stream>>>(eb, gcur, csr, rowptr, rowend);
  spmm1_fused<<<N_NODES / 4, 256, 0, stream>>>(csr, rowptr, rowend,
                                               (const unsigned*)support, b1, h);
  gemm2_kernel<<<(N_NODES + 63) / 64, 256, 0, stream>>>((const uint4*)h, W2,
                                                        h2);
  spmm2_fused<<<N_NODES / 4, 256, 0, stream>>>(csr, rowptr, rowend,
                                               (const unsigned*)h2, b2, out);
}

// Round 6
// 318.114 us; speedup vs baseline: 6.4312x; 1.0407x over previous
//
#include <hip/hip_runtime.h>
#include <hip/hip_bf16.h>

#define N_NODES 50000
#define N_EDGES 1600000
#define NFEAT   512
#define HIDDEN  128
#define NCLASS  40

// 128 rows per bucket -> 391 buckets; bucket id = row >> 7
#define NBUCK 391
#define ROWS_PER_BUCKET 128
#define BUCK_PAD 4608             // mean 4096 + 8 sigma; padded bucket slots

#define W1T_BLOCKS 256
#define GEMM1_BLOCKS 391          // ceil(50000/128)
#define PART_T 4096
#define PART_BLOCKS 391           // ceil(1600000/4096)

// union LDS for the fused partition|gemm1 kernel:
// partition: sorted 32768 | cnt 1564 | shift 1564 | ssc 2048 = 37944
// gemm1:     As 8192 | Bs 8192 = 16384          -> max = 37944 (4 blk/CU)
#define FUSED_LDS 37944

typedef short short8 __attribute__((ext_vector_type(8)));
typedef float f32x4  __attribute__((ext_vector_type(4)));

// bf16 bits (RNE) from float
__device__ __forceinline__ unsigned short f2bu(float f) {
  __hip_bfloat16 h = __float2bfloat16(f);
  return *reinterpret_cast<unsigned short*>(&h);
}

// ---------------------------------------------------------------------------
// JAX threefry2x32, key (0,42), partitionable: bits[i] = o0^o1 of ctr (0,i).
// keep iff (bits>>31)==0.  (verified in earlier rounds)
// ---------------------------------------------------------------------------
__device__ __forceinline__ unsigned rotl32(unsigned x, int n) {
  return (x << n) | (x >> (32 - n));
}

__device__ __forceinline__ unsigned threefry_bits(unsigned x1) {
  unsigned x0 = 0u;
  const unsigned ks0 = 0u, ks1 = 42u, ks2 = 0x1BD11BDAu ^ 42u;
  x0 += ks0; x1 += ks1;
#define TFR(r) { x0 += x1; x1 = rotl32(x1, (r)); x1 ^= x0; }
  TFR(13) TFR(15) TFR(26) TFR(6)
  x0 += ks1; x1 += ks2 + 1u;
  TFR(17) TFR(29) TFR(16) TFR(24)
  x0 += ks2; x1 += ks0 + 2u;
  TFR(13) TFR(15) TFR(26) TFR(6)
  x0 += ks0; x1 += ks1 + 3u;
  TFR(17) TFR(29) TFR(16) TFR(24)
  x0 += ks1; x1 += ks2 + 4u;
  TFR(13) TFR(15) TFR(26) TFR(6)
  x0 += ks2; x1 += ks0 + 5u;
#undef TFR
  return x0 ^ x1;
}

// ---------------------------------------------------------------------------
// K1: W1 transpose (blocks 0..255) | gcur init to padded bucket bases
// (block 256). No histogram/scan needed with padded buckets.
// ---------------------------------------------------------------------------
__global__ __launch_bounds__(256) void init_w1t_kernel(
    const float* __restrict__ W1, unsigned short* __restrict__ W1T,
    int* __restrict__ gcur) {
  if (blockIdx.x < W1T_BLOCKS) {
    int id = blockIdx.x * 256 + threadIdx.x;  // 65536 exact
    int n = id & 127, k = id >> 7;
    W1T[n * NFEAT + k] = f2bu(W1[k * HIDDEN + n]);
  } else {
    int b = threadIdx.x;
    if (b < NBUCK) gcur[b] = b * BUCK_PAD;
    b += 256;
    if (b < NBUCK) gcur[b] = b * BUCK_PAD;
  }
}

// ---------------------------------------------------------------------------
// GEMM1 body (device fn): support = bf16(x) @ bf16(W1), fp32 acc, MFMA.
// (verified; LDS passed in as union buffer)
// ---------------------------------------------------------------------------
__device__ __forceinline__ void gemm1_body(
    int bid, char* smem, const float* __restrict__ x,
    const unsigned short* __restrict__ W1T,
    unsigned short* __restrict__ support) {
  short8* As = (short8*)smem;           // 512 * 16 B, chunk = q*128 + row
  short8* Bs = (short8*)(smem + 8192);  // 512 * 16 B, chunk = q*128 + col
  const int t = threadIdx.x;
  const int lane = t & 63;
  const int w = t >> 6;
  const int quad = lane >> 4;
  const int l15 = lane & 15;
  const int node_base = bid * 128;
  const int mbase = (w >> 1) * 64;
  const int nbase = (w & 1) * 64;

  f32x4 acc[4][4] = {};

  for (int k0 = 0; k0 < NFEAT; k0 += 32) {
#pragma unroll
    for (int i = 0; i < 2; i++) {
      int lin = i * 256 + t;        // 0..511
      int n = lin >> 2, q = lin & 3;
      int row = node_base + n;
      if (row >= N_NODES) row = N_NODES - 1;
      const float* src = &x[(size_t)row * NFEAT + k0 + q * 8];
      float4 a = *(const float4*)src;
      float4 b = *(const float4*)(src + 4);
      short8 p;
      p[0] = (short)f2bu(a.x); p[1] = (short)f2bu(a.y);
      p[2] = (short)f2bu(a.z); p[3] = (short)f2bu(a.w);
      p[4] = (short)f2bu(b.x); p[5] = (short)f2bu(b.y);
      p[6] = (short)f2bu(b.z); p[7] = (short)f2bu(b.w);
      As[q * 128 + n] = p;
      Bs[q * 128 + n] = *(const short8*)&W1T[(size_t)n * NFEAT + k0 + q * 8];
    }
    __syncthreads();
    short8 af[4], bfr[4];
#pragma unroll
    for (int mt = 0; mt < 4; mt++)
      af[mt] = As[quad * 128 + mbase + mt * 16 + l15];
#pragma unroll
    for (int nt = 0; nt < 4; nt++)
      bfr[nt] = Bs[quad * 128 + nbase + nt * 16 + l15];
#pragma unroll
    for (int mt = 0; mt < 4; mt++)
#pragma unroll
      for (int nt = 0; nt < 4; nt++)
        acc[mt][nt] = __builtin_amdgcn_mfma_f32_16x16x32_bf16(
            af[mt], bfr[nt], acc[mt][nt], 0, 0, 0);
    __syncthreads();
  }

#pragma unroll
  for (int mt = 0; mt < 4; mt++)
#pragma unroll
    for (int nt = 0; nt < 4; nt++)
#pragma unroll
      for (int r = 0; r < 4; r++) {
        int row = node_base + mbase + mt * 16 + quad * 4 + r;
        int col = nbase + nt * 16 + l15;
        if (row < N_NODES)
          support[(size_t)row * HIDDEN + col] = f2bu(acc[mt][nt][r]);
      }
}

// ---------------------------------------------------------------------------
// Partition body: LDS counting sort of 4096 edges by bucket -> coalesced
// append into padded bucket regions of eb[] (gcur[b] starts at b*BUCK_PAD).
// Record: uint2 { col | bf16(val)<<16 , row }.
// ---------------------------------------------------------------------------
__device__ __forceinline__ void partition_body(
    int bid, char* smem, const int* __restrict__ erow,
    const int* __restrict__ ecol, const float* __restrict__ evals,
    int* __restrict__ gcur, uint2* __restrict__ eb) {
  uint2* sorted = (uint2*)smem;                  // 4096 * 8 B
  int* cnt   = (int*)(smem + 32768);             // 391 * 4
  int* shift = (int*)(smem + 32768 + 1564);      // 391 * 4
  int* ssc   = (int*)(smem + 32768 + 3128);      // 512 * 4
  const int t = threadIdx.x;
  const int base = bid * PART_T;

  if (t < NBUCK) cnt[t] = 0;
  if (t + 256 < NBUCK) cnt[t + 256] = 0;
  __syncthreads();

  uint2 er[16];
  unsigned short loc[16];
#pragma unroll
  for (int k = 0; k < 16; k++) {
    int idx = base + k * 256 + t;
    if (idx < N_EDGES) {
      int r = erow[idx];
      er[k].y = (unsigned)r;
      er[k].x = (unsigned)ecol[idx] | ((unsigned)f2bu(evals[idx]) << 16);
      loc[k] = (unsigned short)atomicAdd(&cnt[r >> 7], 1);
    } else {
      er[k].y = 0xffffffffu;
    }
  }
  __syncthreads();

  // inclusive scan of cnt (padded to 512)
  ssc[t] = (t < NBUCK) ? cnt[t] : 0;
  ssc[t + 256] = (t + 256 < NBUCK) ? cnt[t + 256] : 0;
  __syncthreads();
#pragma unroll
  for (int off = 1; off < 512; off <<= 1) {
    int v0 = (t >= off) ? ssc[t - off] : 0;
    int v1 = ssc[t + 256 - off];
    __syncthreads();
    ssc[t] += v0; ssc[t + 256] += v1;
    __syncthreads();
  }

  // claim chunk in the padded bucket region
  for (int b = t; b < NBUCK; b += 256) {
    int c = cnt[b];
    if (c > 0) {
      int lb = ssc[b] - c;                  // local base
      int gb = atomicAdd(&gcur[b], c);      // global base of this chunk
      shift[b] = gb - lb;
    }
  }
  // scatter into LDS by bucket (ssc/cnt stable since last barrier)
#pragma unroll
  for (int k = 0; k < 16; k++) {
    if (er[k].y != 0xffffffffu) {
      int b = (int)(er[k].y >> 7);
      sorted[ssc[b] - cnt[b] + (int)loc[k]] = er[k];
    }
  }
  __syncthreads();

  // coalesced copy out: consecutive i share bucket in runs of ~10
  const int total = ssc[NBUCK - 1];
  for (int i = t; i < total; i += 256) {
    uint2 e = sorted[i];
    eb[shift[e.y >> 7] + i] = e;
  }
}

// ---------------------------------------------------------------------------
// K2 fused: partition (blocks 0..390) | GEMM1 (blocks 391..781).
// Union LDS buffer (37.9 KB) -> 4 blocks/CU.
// ---------------------------------------------------------------------------
__global__ __launch_bounds__(256) void part_gemm1_kernel(
    const int* __restrict__ erow, const int* __restrict__ ecol,
    const float* __restrict__ evals, int* __restrict__ gcur,
    uint2* __restrict__ eb, const float* __restrict__ x,
    const unsigned short* __restrict__ W1T,
    unsigned short* __restrict__ support) {
  __shared__ char smem[FUSED_LDS];
  if (blockIdx.x < PART_BLOCKS)
    partition_body(blockIdx.x, smem, erow, ecol, evals, gcur, eb);
  else
    gemm1_body(blockIdx.x - PART_BLOCKS, smem, x, W1T, support);
}

// ---------------------------------------------------------------------------
// K3: exact CSR from padded bucketed edges. Block b owns rows
// [b*128, b*128+128) and eb window [b*BUCK_PAD, gcur[b]). 128-bin LDS
// histogram -> scan -> rowptr/rowend; LDS-cursor scatter into csr (padded
// layout). All scattered writes land in a ~16 KB window.
// ---------------------------------------------------------------------------
__global__ __launch_bounds__(512) void csr_build_kernel(
    const uint2* __restrict__ eb, const int* __restrict__ gcur,
    unsigned* __restrict__ csr, int* __restrict__ rowptr,
    int* __restrict__ rowend) {
  __shared__ int cnt[ROWS_PER_BUCKET];
  __shared__ int sc[ROWS_PER_BUCKET];
  __shared__ int cur[ROWS_PER_BUCKET];
  const int t = threadIdx.x;
  const int b = blockIdx.x;
  if (t < ROWS_PER_BUCKET) cnt[t] = 0;
  __syncthreads();
  const int beg = b * BUCK_PAD;
  const int end = gcur[b];
  for (int j = beg + t; j < end; j += 512)
    atomicAdd(&cnt[eb[j].y & 127u], 1);
  __syncthreads();
  if (t < ROWS_PER_BUCKET) sc[t] = cnt[t];
  __syncthreads();
#pragma unroll
  for (int off = 1; off < ROWS_PER_BUCKET; off <<= 1) {
    int v = 0;
    if (t >= off && t < ROWS_PER_BUCKET) v = sc[t - off];
    __syncthreads();
    if (t < ROWS_PER_BUCKET) sc[t] += v;
    __syncthreads();
  }
  if (t < ROWS_PER_BUCKET) {
    int excl = sc[t] - cnt[t];
    cur[t] = excl;
    int row = b * ROWS_PER_BUCKET + t;
    if (row < N_NODES) {
      rowptr[row] = beg + excl;
      rowend[row] = beg + sc[t];
    }
  }
  __syncthreads();
  for (int j = beg + t; j < end; j += 512) {
    uint2 e = eb[j];
    int p = atomicAdd(&cur[e.y & 127u], 1);
    csr[beg + p] = e.x;
  }
}

// ---------------------------------------------------------------------------
// SpMM1 + GEMM2 fused: wave per row, 16 edges in flight on the gather.
// Epilogue per wave: +b1, relu, threefry dropout -> bf16 h row (held in
// 1 KB LDS, never written to global), then h2[row] = h @ W2 with W2 staged
// in 20 KB LDS (fp32, identical numerics to the old gemm2 kernel).
// ---------------------------------------------------------------------------
__global__ __launch_bounds__(256) void spmm1_fused(
    const unsigned* __restrict__ csr, const int* __restrict__ rowptr,
    const int* __restrict__ rowend,
    const unsigned* __restrict__ sup,  // support rows = 64 uints (bf162)
    const float* __restrict__ b1, const float* __restrict__ W2,
    unsigned* __restrict__ h2u) {     // h2 rows = 20 uints (bf162)
  __shared__ float Ws[HIDDEN * NCLASS];   // 20 KB
  __shared__ unsigned hrow[4][64];        // 1 KB
  const int t = threadIdx.x;
#pragma unroll
  for (int i = 0; i < 20; i++) Ws[i * 256 + t] = W2[i * 256 + t];
  __syncthreads();

  const int row = blockIdx.x * 4 + (t >> 6);
  const int wv = t >> 6;
  const int lane = t & 63;
  const int beg = rowptr[row], end = rowend[row];
  float ax = 0.f, ay = 0.f;
  int j = beg;
  for (; j + 15 < end; j += 16) {
    unsigned p[16], u[16];
#pragma unroll
    for (int k = 0; k < 16; k++) p[k] = csr[j + k];
#pragma unroll
    for (int k = 0; k < 16; k++) u[k] = sup[(p[k] & 0xffffu) * 64 + lane];
#pragma unroll
    for (int k = 0; k < 16; k++) {
      float v = __uint_as_float(p[k] & 0xffff0000u);
      ax += v * __uint_as_float(u[k] << 16);
      ay += v * __uint_as_float(u[k] & 0xffff0000u);
    }
  }
  for (; j + 7 < end; j += 8) {
    unsigned p[8], u[8];
#pragma unroll
    for (int k = 0; k < 8; k++) p[k] = csr[j + k];
#pragma unroll
    for (int k = 0; k < 8; k++) u[k] = sup[(p[k] & 0xffffu) * 64 + lane];
#pragma unroll
    for (int k = 0; k < 8; k++) {
      float v = __uint_as_float(p[k] & 0xffff0000u);
      ax += v * __uint_as_float(u[k] << 16);
      ay += v * __uint_as_float(u[k] & 0xffff0000u);
    }
  }
  for (; j + 1 < end; j += 2) {
    unsigned p0 = csr[j], p1 = csr[j + 1];
    unsigned u0 = sup[(p0 & 0xffffu) * 64 + lane];
    unsigned u1 = sup[(p1 & 0xffffu) * 64 + lane];
    float v0 = __uint_as_float(p0 & 0xffff0000u);
    float v1 = __uint_as_float(p1 & 0xffff0000u);
    ax += v0 * __uint_as_float(u0 << 16) + v1 * __uint_as_float(u1 << 16);
    ay += v0 * __uint_as_float(u0 & 0xffff0000u) +
          v1 * __uint_as_float(u1 & 0xffff0000u);
  }
  if (j < end) {
    unsigned p0 = csr[j];
    unsigned u0 = sup[(p0 & 0xffffu) * 64 + lane];
    float v0 = __uint_as_float(p0 & 0xffff0000u);
    ax += v0 * __uint_as_float(u0 << 16);
    ay += v0 * __uint_as_float(u0 & 0xffff0000u);
  }
  const unsigned i0 = (unsigned)row * HIDDEN + lane * 2;
  float vx = fmaxf(ax + b1[lane * 2], 0.f);
  float vy = fmaxf(ay + b1[lane * 2 + 1], 0.f);
  vx = (threefry_bits(i0) >> 31) ? 0.f : 2.f * vx;
  vy = (threefry_bits(i0 + 1) >> 31) ? 0.f : 2.f * vy;
  hrow[wv][lane] = (unsigned)f2bu(vx) | ((unsigned)f2bu(vy) << 16);
  __syncthreads();

  // gemm2 tail: lane c (<40) computes h2[row][c] = sum_k h[k] * W2[k][c]
  float accv = 0.f;
  if (lane < NCLASS) {
#pragma unroll 8
    for (int i = 0; i < 64; i++) {
      unsigned u = hrow[wv][i];
      float h0 = __uint_as_float(u << 16);
      float h1 = __uint_as_float(u & 0xffff0000u);
      accv += h0 * Ws[(2 * i) * NCLASS + lane] +
              h1 * Ws[(2 * i + 1) * NCLASS + lane];
    }
    float other = __shfl_xor(accv, 1);
    if (!(lane & 1))
      h2u[(unsigned)row * 20 + (lane >> 1)] =
          (unsigned)f2bu(accv) | ((unsigned)f2bu(other) << 16);
  }
}

// ---------------------------------------------------------------------------
// SpMM2 fused: wave per row, half-split x 4-unroll = 8 edges in flight.
// ---------------------------------------------------------------------------
__global__ __launch_bounds__(256) void spmm2_fused(
    const unsigned* __restrict__ csr, const int* __restrict__ rowptr,
    const int* __restrict__ rowend,
    const unsigned* __restrict__ h2u,  // rows = 20 uints
    const float* __restrict__ b2, float* __restrict__ out) {
  const int row = blockIdx.x * 4 + (threadIdx.x >> 6);
  const int lane = threadIdx.x & 63;
  const int half = lane >> 5;
  const int il = lane & 31;
  const unsigned ilc = (il < 20) ? (unsigned)il : 19u;
  const int beg = rowptr[row], end = rowend[row];
  float ax = 0.f, ay = 0.f;
  int j = beg + half;
  for (; j + 6 < end; j += 8) {
    unsigned p[4], u[4];
#pragma unroll
    for (int k = 0; k < 4; k++) p[k] = csr[j + 2 * k];
#pragma unroll
    for (int k = 0; k < 4; k++) u[k] = h2u[(p[k] & 0xffffu) * 20 + ilc];
#pragma unroll
    for (int k = 0; k < 4; k++) {
      float v = __uint_as_float(p[k] & 0xffff0000u);
      ax += v * __uint_as_float(u[k] << 16);
      ay += v * __uint_as_float(u[k] & 0xffff0000u);
    }
  }
  for (; j + 2 < end; j += 4) {
    unsigned p0 = csr[j];
    unsigned p1 = csr[j + 2];
    unsigned u0 = h2u[(p0 & 0xffffu) * 20 + ilc];
    unsigned u1 = h2u[(p1 & 0xffffu) * 20 + ilc];
    float v0 = __uint_as_float(p0 & 0xffff0000u);
    float v1 = __uint_as_float(p1 & 0xffff0000u);
    ax += v0 * __uint_as_float(u0 << 16) + v1 * __uint_as_float(u1 << 16);
    ay += v0 * __uint_as_float(u0 & 0xffff0000u) +
          v1 * __uint_as_float(u1 & 0xffff0000u);
  }
  for (; j < end; j += 2) {
    unsigned p0 = csr[j];
    unsigned u0 = h2u[(p0 & 0xffffu) * 20 + ilc];
    float v0 = __uint_as_float(p0 & 0xffff0000u);
    ax += v0 * __uint_as_float(u0 << 16);
    ay += v0 * __uint_as_float(u0 & 0xffff0000u);
  }
  ax += __shfl_xor(ax, 32);
  ay += __shfl_xor(ay, 32);
  if (half == 0 && il < 20) {
    float2 r;
    r.x = fmaxf(ax + b2[il * 2], 0.f);
    r.y = fmaxf(ay + b2[il * 2 + 1], 0.f);
    *(float2*)&out[(unsigned)row * NCLASS + il * 2] = r;
  }
}

extern "C" void kernel_launch(void* const* d_in, const int* in_sizes, int n_in,
                              void* d_out, int out_size, void* d_ws,
                              size_t ws_size, hipStream_t stream) {
  const float* x     = (const float*)d_in[0];
  const int*   erow  = (const int*)d_in[1];
  const int*   ecol  = (const int*)d_in[2];
  const float* evals = (const float*)d_in[3];
  const float* W1    = (const float*)d_in[4];
  const float* b1    = (const float*)d_in[5];
  const float* W2    = (const float*)d_in[6];
  const float* b2    = (const float*)d_in[7];
  float* out = (float*)d_out;

  // ws layout (bytes):
  //   support 12.8M @ 0
  //   eb (padded, 391*4608*8 = 14,413,824) @ 12,800,000
  //   h2 4M @ 27,213,824 | W1T 128K @ 31,213,824
  //   csr (padded, 7,206,912) @ 31,344,896
  //   rowptr 200K @ 38,551,808 | rowend 200K @ 38,751,808
  //   gcur 1.6K @ 38,951,808        (~39 MB total)
  char* base = (char*)d_ws;
  unsigned short* support = (unsigned short*)base;
  uint2*          eb  = (uint2*)(base + 12800000);
  unsigned*       h2  = (unsigned*)(base + 27213824);
  unsigned short* W1T = (unsigned short*)(base + 31213824);
  unsigned*       csr = (unsigned*)(base + 31344896);
  int* rowptr = (int*)(base + 38551808);
  int* rowend = (int*)(base + 38751808);
  int* gcur   = (int*)(base + 38951808);

  init_w1t_kernel<<<W1T_BLOCKS + 1, 256, 0, stream>>>(W1, W1T, gcur);
  part_gemm1_kernel<<<PART_BLOCKS + GEMM1_BLOCKS, 256, 0, stream>>>(
      erow, ecol, evals, gcur, eb, x, W1T, support);
  csr_build_kernel<<<NBUCK, 512, 0, stream>>>(eb, gcur, csr, rowptr, rowend);
  spmm1_fused<<<N_NODES / 4, 256, 0, stream>>>(
      csr, rowptr, rowend, (const unsigned*)support, b1, W2, h2);
  spmm2_fused<<<N_NODES / 4, 256, 0, stream>>>(csr, rowptr, rowend,
                                               (const unsigned*)h2, b2, out);
}

// Round 7
// 313.267 us; speedup vs baseline: 6.5307x; 1.0155x over previous
//
#include <hip/hip_runtime.h>
#include <hip/hip_bf16.h>

#define N_NODES 50000
#define N_EDGES 1600000
#define NFEAT   512
#define HIDDEN  128
#define NCLASS  40

// 128 rows per bucket -> 391 buckets; bucket id = row >> 7
#define NBUCK 391
#define ROWS_PER_BUCKET 128
#define BUCK_PAD 4608             // mean 4096 + 8 sigma; padded bucket slots

#define W1T_BLOCKS 256
#define GEMM1_BLOCKS 391          // ceil(50000/128)
#define PART_T 4096
#define PART_BLOCKS 391           // ceil(1600000/4096)

// union LDS for the fused partition|gemm1 kernel:
// partition: sorted 32768 | cnt 1564 | shift 1564 | ssc 2048 = 37944
// gemm1:     As 8192 | Bs 8192 = 16384          -> max = 37944 (4 blk/CU)
#define FUSED_LDS 37944

typedef short short8 __attribute__((ext_vector_type(8)));
typedef float f32x4  __attribute__((ext_vector_type(4)));

// bf16 bits (RNE) from float
__device__ __forceinline__ unsigned short f2bu(float f) {
  __hip_bfloat16 h = __float2bfloat16(f);
  return *reinterpret_cast<unsigned short*>(&h);
}

// ---------------------------------------------------------------------------
// JAX threefry2x32, key (0,42), partitionable: bits[i] = o0^o1 of ctr (0,i).
// keep iff (bits>>31)==0.  (verified in earlier rounds)
// ---------------------------------------------------------------------------
__device__ __forceinline__ unsigned rotl32(unsigned x, int n) {
  return (x << n) | (x >> (32 - n));
}

__device__ __forceinline__ unsigned threefry_bits(unsigned x1) {
  unsigned x0 = 0u;
  const unsigned ks0 = 0u, ks1 = 42u, ks2 = 0x1BD11BDAu ^ 42u;
  x0 += ks0; x1 += ks1;
#define TFR(r) { x0 += x1; x1 = rotl32(x1, (r)); x1 ^= x0; }
  TFR(13) TFR(15) TFR(26) TFR(6)
  x0 += ks1; x1 += ks2 + 1u;
  TFR(17) TFR(29) TFR(16) TFR(24)
  x0 += ks2; x1 += ks0 + 2u;
  TFR(13) TFR(15) TFR(26) TFR(6)
  x0 += ks0; x1 += ks1 + 3u;
  TFR(17) TFR(29) TFR(16) TFR(24)
  x0 += ks1; x1 += ks2 + 4u;
  TFR(13) TFR(15) TFR(26) TFR(6)
  x0 += ks2; x1 += ks0 + 5u;
#undef TFR
  return x0 ^ x1;
}

// ---------------------------------------------------------------------------
// K1: W1 transpose (blocks 0..255) | gcur init to padded bucket bases
// (block 256). No histogram/scan needed with padded buckets.
// ---------------------------------------------------------------------------
__global__ __launch_bounds__(256) void init_w1t_kernel(
    const float* __restrict__ W1, unsigned short* __restrict__ W1T,
    int* __restrict__ gcur) {
  if (blockIdx.x < W1T_BLOCKS) {
    int id = blockIdx.x * 256 + threadIdx.x;  // 65536 exact
    int n = id & 127, k = id >> 7;
    W1T[n * NFEAT + k] = f2bu(W1[k * HIDDEN + n]);
  } else {
    int b = threadIdx.x;
    if (b < NBUCK) gcur[b] = b * BUCK_PAD;
    b += 256;
    if (b < NBUCK) gcur[b] = b * BUCK_PAD;
  }
}

// ---------------------------------------------------------------------------
// GEMM1 body (device fn): support = bf16(x) @ bf16(W1), fp32 acc, MFMA.
// (verified; LDS passed in as union buffer)
// ---------------------------------------------------------------------------
__device__ __forceinline__ void gemm1_body(
    int bid, char* smem, const float* __restrict__ x,
    const unsigned short* __restrict__ W1T,
    unsigned short* __restrict__ support) {
  short8* As = (short8*)smem;           // 512 * 16 B, chunk = q*128 + row
  short8* Bs = (short8*)(smem + 8192);  // 512 * 16 B, chunk = q*128 + col
  const int t = threadIdx.x;
  const int lane = t & 63;
  const int w = t >> 6;
  const int quad = lane >> 4;
  const int l15 = lane & 15;
  const int node_base = bid * 128;
  const int mbase = (w >> 1) * 64;
  const int nbase = (w & 1) * 64;

  f32x4 acc[4][4] = {};

  for (int k0 = 0; k0 < NFEAT; k0 += 32) {
#pragma unroll
    for (int i = 0; i < 2; i++) {
      int lin = i * 256 + t;        // 0..511
      int n = lin >> 2, q = lin & 3;
      int row = node_base + n;
      if (row >= N_NODES) row = N_NODES - 1;
      const float* src = &x[(size_t)row * NFEAT + k0 + q * 8];
      float4 a = *(const float4*)src;
      float4 b = *(const float4*)(src + 4);
      short8 p;
      p[0] = (short)f2bu(a.x); p[1] = (short)f2bu(a.y);
      p[2] = (short)f2bu(a.z); p[3] = (short)f2bu(a.w);
      p[4] = (short)f2bu(b.x); p[5] = (short)f2bu(b.y);
      p[6] = (short)f2bu(b.z); p[7] = (short)f2bu(b.w);
      As[q * 128 + n] = p;
      Bs[q * 128 + n] = *(const short8*)&W1T[(size_t)n * NFEAT + k0 + q * 8];
    }
    __syncthreads();
    short8 af[4], bfr[4];
#pragma unroll
    for (int mt = 0; mt < 4; mt++)
      af[mt] = As[quad * 128 + mbase + mt * 16 + l15];
#pragma unroll
    for (int nt = 0; nt < 4; nt++)
      bfr[nt] = Bs[quad * 128 + nbase + nt * 16 + l15];
#pragma unroll
    for (int mt = 0; mt < 4; mt++)
#pragma unroll
      for (int nt = 0; nt < 4; nt++)
        acc[mt][nt] = __builtin_amdgcn_mfma_f32_16x16x32_bf16(
            af[mt], bfr[nt], acc[mt][nt], 0, 0, 0);
    __syncthreads();
  }

#pragma unroll
  for (int mt = 0; mt < 4; mt++)
#pragma unroll
    for (int nt = 0; nt < 4; nt++)
#pragma unroll
      for (int r = 0; r < 4; r++) {
        int row = node_base + mbase + mt * 16 + quad * 4 + r;
        int col = nbase + nt * 16 + l15;
        if (row < N_NODES)
          support[(size_t)row * HIDDEN + col] = f2bu(acc[mt][nt][r]);
      }
}

// ---------------------------------------------------------------------------
// Partition body: LDS counting sort of 4096 edges by bucket -> coalesced
// append into padded bucket regions of eb[] (gcur[b] starts at b*BUCK_PAD).
// Record: uint2 { col | bf16(val)<<16 , row }.
// ---------------------------------------------------------------------------
__device__ __forceinline__ void partition_body(
    int bid, char* smem, const int* __restrict__ erow,
    const int* __restrict__ ecol, const float* __restrict__ evals,
    int* __restrict__ gcur, uint2* __restrict__ eb) {
  uint2* sorted = (uint2*)smem;                  // 4096 * 8 B
  int* cnt   = (int*)(smem + 32768);             // 391 * 4
  int* shift = (int*)(smem + 32768 + 1564);      // 391 * 4
  int* ssc   = (int*)(smem + 32768 + 3128);      // 512 * 4
  const int t = threadIdx.x;
  const int base = bid * PART_T;

  if (t < NBUCK) cnt[t] = 0;
  if (t + 256 < NBUCK) cnt[t + 256] = 0;
  __syncthreads();

  uint2 er[16];
  unsigned short loc[16];
#pragma unroll
  for (int k = 0; k < 16; k++) {
    int idx = base + k * 256 + t;
    if (idx < N_EDGES) {
      int r = erow[idx];
      er[k].y = (unsigned)r;
      er[k].x = (unsigned)ecol[idx] | ((unsigned)f2bu(evals[idx]) << 16);
      loc[k] = (unsigned short)atomicAdd(&cnt[r >> 7], 1);
    } else {
      er[k].y = 0xffffffffu;
    }
  }
  __syncthreads();

  // inclusive scan of cnt (padded to 512)
  ssc[t] = (t < NBUCK) ? cnt[t] : 0;
  ssc[t + 256] = (t + 256 < NBUCK) ? cnt[t + 256] : 0;
  __syncthreads();
#pragma unroll
  for (int off = 1; off < 512; off <<= 1) {
    int v0 = (t >= off) ? ssc[t - off] : 0;
    int v1 = ssc[t + 256 - off];
    __syncthreads();
    ssc[t] += v0; ssc[t + 256] += v1;
    __syncthreads();
  }

  // claim chunk in the padded bucket region
  for (int b = t; b < NBUCK; b += 256) {
    int c = cnt[b];
    if (c > 0) {
      int lb = ssc[b] - c;                  // local base
      int gb = atomicAdd(&gcur[b], c);      // global base of this chunk
      shift[b] = gb - lb;
    }
  }
  // scatter into LDS by bucket (ssc/cnt stable since last barrier)
#pragma unroll
  for (int k = 0; k < 16; k++) {
    if (er[k].y != 0xffffffffu) {
      int b = (int)(er[k].y >> 7);
      sorted[ssc[b] - cnt[b] + (int)loc[k]] = er[k];
    }
  }
  __syncthreads();

  // coalesced copy out: consecutive i share bucket in runs of ~10
  const int total = ssc[NBUCK - 1];
  for (int i = t; i < total; i += 256) {
    uint2 e = sorted[i];
    eb[shift[e.y >> 7] + i] = e;
  }
}

// ---------------------------------------------------------------------------
// K2 fused: partition (blocks 0..390) | GEMM1 (blocks 391..781).
// Union LDS buffer (37.9 KB) -> 4 blocks/CU.
// ---------------------------------------------------------------------------
__global__ __launch_bounds__(256) void part_gemm1_kernel(
    const int* __restrict__ erow, const int* __restrict__ ecol,
    const float* __restrict__ evals, int* __restrict__ gcur,
    uint2* __restrict__ eb, const float* __restrict__ x,
    const unsigned short* __restrict__ W1T,
    unsigned short* __restrict__ support) {
  __shared__ char smem[FUSED_LDS];
  if (blockIdx.x < PART_BLOCKS)
    partition_body(blockIdx.x, smem, erow, ecol, evals, gcur, eb);
  else
    gemm1_body(blockIdx.x - PART_BLOCKS, smem, x, W1T, support);
}

// ---------------------------------------------------------------------------
// K3: exact CSR from padded bucketed edges. Block b owns rows
// [b*128, b*128+128) and eb window [b*BUCK_PAD, gcur[b]). 128-bin LDS
// histogram -> scan -> rowptr/rowend; LDS-cursor scatter into csr (padded
// layout). All scattered writes land in a ~16 KB window.
// ---------------------------------------------------------------------------
__global__ __launch_bounds__(512) void csr_build_kernel(
    const uint2* __restrict__ eb, const int* __restrict__ gcur,
    unsigned* __restrict__ csr, int* __restrict__ rowptr,
    int* __restrict__ rowend) {
  __shared__ int cnt[ROWS_PER_BUCKET];
  __shared__ int sc[ROWS_PER_BUCKET];
  __shared__ int cur[ROWS_PER_BUCKET];
  const int t = threadIdx.x;
  const int b = blockIdx.x;
  if (t < ROWS_PER_BUCKET) cnt[t] = 0;
  __syncthreads();
  const int beg = b * BUCK_PAD;
  const int end = gcur[b];
  for (int j = beg + t; j < end; j += 512)
    atomicAdd(&cnt[eb[j].y & 127u], 1);
  __syncthreads();
  if (t < ROWS_PER_BUCKET) sc[t] = cnt[t];
  __syncthreads();
#pragma unroll
  for (int off = 1; off < ROWS_PER_BUCKET; off <<= 1) {
    int v = 0;
    if (t >= off && t < ROWS_PER_BUCKET) v = sc[t - off];
    __syncthreads();
    if (t < ROWS_PER_BUCKET) sc[t] += v;
    __syncthreads();
  }
  if (t < ROWS_PER_BUCKET) {
    int excl = sc[t] - cnt[t];
    cur[t] = excl;
    int row = b * ROWS_PER_BUCKET + t;
    if (row < N_NODES) {
      rowptr[row] = beg + excl;
      rowend[row] = beg + sc[t];
    }
  }
  __syncthreads();
  for (int j = beg + t; j < end; j += 512) {
    uint2 e = eb[j];
    int p = atomicAdd(&cur[e.y & 127u], 1);
    csr[beg + p] = e.x;
  }
}

// ---------------------------------------------------------------------------
// SpMM1 + GEMM2 fused: wave per row. Edge stream is wave-uniform ->
// readfirstlane moves col/val extraction and gather-base math to the
// scalar pipe (SALU), leaving only bf16 unpack + 2 FMA on the VALU.
// Epilogue: +b1, relu, dropout -> bf16 h row in LDS, then h2 = h @ W2
// with W2 staged in 20 KB LDS.
// ---------------------------------------------------------------------------
__global__ __launch_bounds__(256) void spmm1_fused(
    const unsigned* __restrict__ csr, const int* __restrict__ rowptr,
    const int* __restrict__ rowend,
    const unsigned* __restrict__ sup,  // support rows = 64 uints (bf162)
    const float* __restrict__ b1, const float* __restrict__ W2,
    unsigned* __restrict__ h2u) {     // h2 rows = 20 uints (bf162)
  __shared__ float Ws[HIDDEN * NCLASS];   // 20 KB
  __shared__ unsigned hrow[4][64];        // 1 KB
  const int t = threadIdx.x;
#pragma unroll
  for (int i = 0; i < 20; i++) Ws[i * 256 + t] = W2[i * 256 + t];
  __syncthreads();

  const int row = blockIdx.x * 4 + (t >> 6);
  const int wv = t >> 6;
  const int lane = t & 63;
  const int beg = __builtin_amdgcn_readfirstlane(rowptr[row]);
  const int end = __builtin_amdgcn_readfirstlane(rowend[row]);
  float ax = 0.f, ay = 0.f;
  int j = beg;
  for (; j + 15 < end; j += 16) {
    unsigned ps[16];
#pragma unroll
    for (int k = 0; k < 16; k++)
      ps[k] = __builtin_amdgcn_readfirstlane(csr[j + k]);
    unsigned u[16];
#pragma unroll
    for (int k = 0; k < 16; k++)
      u[k] = sup[(size_t)(ps[k] & 0xffffu) * 64 + lane];
#pragma unroll
    for (int k = 0; k < 16; k++) {
      float v = __uint_as_float(ps[k] & 0xffff0000u);
      ax += v * __uint_as_float(u[k] << 16);
      ay += v * __uint_as_float(u[k] & 0xffff0000u);
    }
  }
  for (; j + 7 < end; j += 8) {
    unsigned ps[8];
#pragma unroll
    for (int k = 0; k < 8; k++)
      ps[k] = __builtin_amdgcn_readfirstlane(csr[j + k]);
    unsigned u[8];
#pragma unroll
    for (int k = 0; k < 8; k++)
      u[k] = sup[(size_t)(ps[k] & 0xffffu) * 64 + lane];
#pragma unroll
    for (int k = 0; k < 8; k++) {
      float v = __uint_as_float(ps[k] & 0xffff0000u);
      ax += v * __uint_as_float(u[k] << 16);
      ay += v * __uint_as_float(u[k] & 0xffff0000u);
    }
  }
  for (; j + 1 < end; j += 2) {
    unsigned p0 = __builtin_amdgcn_readfirstlane(csr[j]);
    unsigned p1 = __builtin_amdgcn_readfirstlane(csr[j + 1]);
    unsigned u0 = sup[(size_t)(p0 & 0xffffu) * 64 + lane];
    unsigned u1 = sup[(size_t)(p1 & 0xffffu) * 64 + lane];
    float v0 = __uint_as_float(p0 & 0xffff0000u);
    float v1 = __uint_as_float(p1 & 0xffff0000u);
    ax += v0 * __uint_as_float(u0 << 16) + v1 * __uint_as_float(u1 << 16);
    ay += v0 * __uint_as_float(u0 & 0xffff0000u) +
          v1 * __uint_as_float(u1 & 0xffff0000u);
  }
  if (j < end) {
    unsigned p0 = __builtin_amdgcn_readfirstlane(csr[j]);
    unsigned u0 = sup[(size_t)(p0 & 0xffffu) * 64 + lane];
    float v0 = __uint_as_float(p0 & 0xffff0000u);
    ax += v0 * __uint_as_float(u0 << 16);
    ay += v0 * __uint_as_float(u0 & 0xffff0000u);
  }
  const unsigned i0 = (unsigned)row * HIDDEN + lane * 2;
  float vx = fmaxf(ax + b1[lane * 2], 0.f);
  float vy = fmaxf(ay + b1[lane * 2 + 1], 0.f);
  vx = (threefry_bits(i0) >> 31) ? 0.f : 2.f * vx;
  vy = (threefry_bits(i0 + 1) >> 31) ? 0.f : 2.f * vy;
  hrow[wv][lane] = (unsigned)f2bu(vx) | ((unsigned)f2bu(vy) << 16);
  __syncthreads();

  // gemm2 tail: lane c (<40) computes h2[row][c] = sum_k h[k] * W2[k][c]
  float accv = 0.f;
  if (lane < NCLASS) {
#pragma unroll 8
    for (int i = 0; i < 64; i++) {
      unsigned u = hrow[wv][i];
      float h0 = __uint_as_float(u << 16);
      float h1 = __uint_as_float(u & 0xffff0000u);
      accv += h0 * Ws[(2 * i) * NCLASS + lane] +
              h1 * Ws[(2 * i + 1) * NCLASS + lane];
    }
    float other = __shfl_xor(accv, 1);
    if (!(lane & 1))
      h2u[(unsigned)row * 20 + (lane >> 1)] =
          (unsigned)f2bu(accv) | ((unsigned)f2bu(other) << 16);
  }
}

// ---------------------------------------------------------------------------
// SpMM2 fused: wave per row, half-split x 4-unroll = 8 edges in flight.
// (readfirstlane NOT applicable: j differs between lane-halves.)
// ---------------------------------------------------------------------------
__global__ __launch_bounds__(256) void spmm2_fused(
    const unsigned* __restrict__ csr, const int* __restrict__ rowptr,
    const int* __restrict__ rowend,
    const unsigned* __restrict__ h2u,  // rows = 20 uints
    const float* __restrict__ b2, float* __restrict__ out) {
  const int row = blockIdx.x * 4 + (threadIdx.x >> 6);
  const int lane = threadIdx.x & 63;
  const int half = lane >> 5;
  const int il = lane & 31;
  const unsigned ilc = (il < 20) ? (unsigned)il : 19u;
  const int beg = rowptr[row], end = rowend[row];
  float ax = 0.f, ay = 0.f;
  int j = beg + half;
  for (; j + 6 < end; j += 8) {
    unsigned p[4], u[4];
#pragma unroll
    for (int k = 0; k < 4; k++) p[k] = csr[j + 2 * k];
#pragma unroll
    for (int k = 0; k < 4; k++) u[k] = h2u[(p[k] & 0xffffu) * 20 + ilc];
#pragma unroll
    for (int k = 0; k < 4; k++) {
      float v = __uint_as_float(p[k] & 0xffff0000u);
      ax += v * __uint_as_float(u[k] << 16);
      ay += v * __uint_as_float(u[k] & 0xffff0000u);
    }
  }
  for (; j + 2 < end; j += 4) {
    unsigned p0 = csr[j];
    unsigned p1 = csr[j + 2];
    unsigned u0 = h2u[(p0 & 0xffffu) * 20 + ilc];
    unsigned u1 = h2u[(p1 & 0xffffu) * 20 + ilc];
    float v0 = __uint_as_float(p0 & 0xffff0000u);
    float v1 = __uint_as_float(p1 & 0xffff0000u);
    ax += v0 * __uint_as_float(u0 << 16) + v1 * __uint_as_float(u1 << 16);
    ay += v0 * __uint_as_float(u0 & 0xffff0000u) +
          v1 * __uint_as_float(u1 & 0xffff0000u);
  }
  for (; j < end; j += 2) {
    unsigned p0 = csr[j];
    unsigned u0 = h2u[(p0 & 0xffffu) * 20 + ilc];
    float v0 = __uint_as_float(p0 & 0xffff0000u);
    ax += v0 * __uint_as_float(u0 << 16);
    ay += v0 * __uint_as_float(u0 & 0xffff0000u);
  }
  ax += __shfl_xor(ax, 32);
  ay += __shfl_xor(ay, 32);
  if (half == 0 && il < 20) {
    float2 r;
    r.x = fmaxf(ax + b2[il * 2], 0.f);
    r.y = fmaxf(ay + b2[il * 2 + 1], 0.f);
    *(float2*)&out[(unsigned)row * NCLASS + il * 2] = r;
  }
}

extern "C" void kernel_launch(void* const* d_in, const int* in_sizes, int n_in,
                              void* d_out, int out_size, void* d_ws,
                              size_t ws_size, hipStream_t stream) {
  const float* x     = (const float*)d_in[0];
  const int*   erow  = (const int*)d_in[1];
  const int*   ecol  = (const int*)d_in[2];
  const float* evals = (const float*)d_in[3];
  const float* W1    = (const float*)d_in[4];
  const float* b1    = (const float*)d_in[5];
  const float* W2    = (const float*)d_in[6];
  const float* b2    = (const float*)d_in[7];
  float* out = (float*)d_out;

  // ws layout (bytes):
  //   support 12.8M @ 0
  //   eb (padded, 391*4608*8 = 14,413,824) @ 12,800,000
  //   h2 4M @ 27,213,824 | W1T 128K @ 31,213,824
  //   csr (padded, 7,206,912) @ 31,344,896
  //   rowptr 200K @ 38,551,808 | rowend 200K @ 38,751,808
  //   gcur 1.6K @ 38,951,808        (~39 MB total)
  char* base = (char*)d_ws;
  unsigned short* support = (unsigned short*)base;
  uint2*          eb  = (uint2*)(base + 12800000);
  unsigned*       h2  = (unsigned*)(base + 27213824);
  unsigned short* W1T = (unsigned short*)(base + 31213824);
  unsigned*       csr = (unsigned*)(base + 31344896);
  int* rowptr = (int*)(base + 38551808);
  int* rowend = (int*)(base + 38751808);
  int* gcur   = (int*)(base + 38951808);

  init_w1t_kernel<<<W1T_BLOCKS + 1, 256, 0, stream>>>(W1, W1T, gcur);
  part_gemm1_kernel<<<PART_BLOCKS + GEMM1_BLOCKS, 256, 0, stream>>>(
      erow, ecol, evals, gcur, eb, x, W1T, support);
  csr_build_kernel<<<NBUCK, 512, 0, stream>>>(eb, gcur, csr, rowptr, rowend);
  spmm1_fused<<<N_NODES / 4, 256, 0, stream>>>(
      csr, rowptr, rowend, (const unsigned*)support, b1, W2, h2);
  spmm2_fused<<<N_NODES / 4, 256, 0, stream>>>(csr, rowptr, rowend,
                                               (const unsigned*)h2, b2, out);
}